// Round 2
// baseline (2128.860 us; speedup 1.0000x reference)
//
#include <hip/hip_runtime.h>
#include <hip/hip_bf16.h>

// Problem constants
#define BB 8
#define HH 192
#define WW 192
#define CC0 64          // input channels of prv/nxt
#define NPIX (BB*HH*WW) // 294912
#define CIN0 209        // 81 + 64 + 64
#define NCV 81

typedef struct __align__(8) { __hip_bfloat16 x, y, z, w; } bf16x4;

__device__ __forceinline__ float mish_f(float v) {
    // mish(v) = v * tanh(softplus(v)) = v * (u^2 + 2u) / (u^2 + 2u + 2), u = e^v
    if (v > 20.0f) return v;               // tanh(softplus) == 1 to f32 precision
    const float u = __expf(v);
    const float n = u * (u + 2.0f);
    return v * n / (n + 2.0f);
}

// ---------------------------------------------------------------------------
// Kernel 1: cost volume (81 shifts, mean over 64 ch, leaky 0.1) -> bf16 [N,81]
// One block per (b,h) row; 192 threads = one per w.
// Per phase r (9 phases): stage nxt row y=h-4+r (cols -4..195, 64ch) in LDS,
// padded to 68 floats/pixel so lane-consecutive float4 reads are conflict-free.
// ---------------------------------------------------------------------------
__global__ __launch_bounds__(192) void cost_kernel(
    const float* __restrict__ prv, const float* __restrict__ nxt,
    __hip_bfloat16* __restrict__ x0cv)
{
    const int w = threadIdx.x;
    const int h = blockIdx.x;
    const int b = blockIdx.y;
    __shared__ float4 srow[200 * 17];   // 200 px * 68 floats = 54.4 KB

    const size_t pixbase = ((size_t)b * HH + h) * WW + w;
    const float* pptr = prv + pixbase * CC0;
    float4 p[16];
#pragma unroll
    for (int cc = 0; cc < 16; ++cc) p[cc] = *(const float4*)(pptr + cc * 4);

    const size_t obase = pixbase * NCV;

    for (int r = 0; r < 9; ++r) {
        __syncthreads();   // protect previous phase's LDS reads
        const int y = h - 4 + r;
        const bool yok = ((unsigned)y < HH);
        const float* rowp = nxt + (((size_t)b * HH + y) * WW) * CC0;
        for (int idx = w; idx < 200 * 16; idx += 192) {
            const int col = idx >> 4;
            const int cc  = idx & 15;
            const int x   = col - 4;
            float4 v = make_float4(0.f, 0.f, 0.f, 0.f);
            if (yok && (unsigned)x < WW)
                v = *(const float4*)(rowp + (size_t)x * CC0 + cc * 4);
            srow[col * 17 + cc] = v;
        }
        __syncthreads();
#pragma unroll
        for (int dj = 0; dj < 9; ++dj) {
            const float4* sp = &srow[(w + dj) * 17];
            float s = 0.f;
#pragma unroll
            for (int cc = 0; cc < 16; ++cc) {
                const float4 nv = sp[cc];
                s += p[cc].x * nv.x; s += p[cc].y * nv.y;
                s += p[cc].z * nv.z; s += p[cc].w * nv.w;
            }
            const float m = s * (1.0f / 64.0f);
            x0cv[obase + r * 9 + dj] = __float2bfloat16((m > 0.f) ? m : 0.1f * m);
        }
    }
}

// ---------------------------------------------------------------------------
// Fused sepconv = depthwise3x3 (on the fly into LDS, f32) -> pointwise GEMM
// (4x4 register tile, f32 acc) -> +bias -> mish -> bf16 out.
// Stage 0 variant reads its 209 "virtual" input channels from three sources:
// c<81: cost volume (bf16), 81<=c<145: prv (f32), c>=145: nxt (f32).
// ---------------------------------------------------------------------------
template<int CIN, int COUT, int STAGE0>
__global__ __launch_bounds__(256) void sepconv_kernel(
    const __hip_bfloat16* __restrict__ in,   // bf16 input (stage>=1) or cost vol (stage0)
    const float* __restrict__ prv, const float* __restrict__ nxt,  // stage0 only
    const float* __restrict__ dwW,
    const float* __restrict__ pwW, const float* __restrict__ bias,
    __hip_bfloat16* __restrict__ out)
{
    constexpr int KC  = 32;
    constexpr int TX  = COUT / 4;
    constexpr int PY  = 256 / TX;
    constexpr int PXT = PY * 4;
    __shared__ float sA[KC][PXT];
    __shared__ float sB[KC][COUT];
    const int tid = threadIdx.x;
    const int tx  = tid % TX;
    const int ty  = tid / TX;
    const int p0  = blockIdx.x * PXT;
    float acc[4][4] = {};

    for (int k0 = 0; k0 < CIN; k0 += KC) {
        const int kc = (CIN - k0 < KC) ? (CIN - k0) : KC;
        // stage pointwise weight chunk
        for (int idx = tid; idx < kc * COUT; idx += 256) {
            const int k  = idx / COUT;
            const int co = idx - k * COUT;
            sB[k][co] = pwW[(size_t)(k0 + k) * COUT + co];
        }
        // stage depthwise output chunk (fused: no dw intermediate in HBM)
        for (int idx = tid; idx < kc * PXT; idx += 256) {
            int px, k;
            if (kc == KC) { px = idx >> 5; k = idx & 31; }
            else          { px = idx / kc; k = idx - px * kc; }
            const int c   = k0 + k;
            const int pix = p0 + px;
            const int wq  = pix % WW;
            const int hq  = (pix / WW) % HH;
            const int bq  = pix / (WW * HH);
            float s = 0.f;
#pragma unroll
            for (int dy = -1; dy <= 1; ++dy) {
                const int yy = hq + dy;
                if ((unsigned)yy >= HH) continue;
#pragma unroll
                for (int dx = -1; dx <= 1; ++dx) {
                    const int xx = wq + dx;
                    if ((unsigned)xx >= WW) continue;
                    const size_t nidx = ((size_t)bq * HH + yy) * WW + xx;
                    float v;
                    if (STAGE0) {
                        if (c < NCV)            v = __bfloat162float(in[nidx * NCV + c]);
                        else if (c < NCV + CC0) v = prv[nidx * CC0 + (c - NCV)];
                        else                    v = nxt[nidx * CC0 + (c - NCV - CC0)];
                    } else {
                        v = __bfloat162float(in[nidx * CIN + c]);
                    }
                    s += v * dwW[((dy + 1) * 3 + (dx + 1)) * CIN + c];
                }
            }
            sA[k][px] = s;
        }
        __syncthreads();
#define GEMM_STEP(kk) {                                                     \
            const float4 av = *(const float4*)&sA[kk][ty * 4];              \
            const float4 bv = *(const float4*)&sB[kk][tx * 4];              \
            acc[0][0] += av.x * bv.x; acc[0][1] += av.x * bv.y;             \
            acc[0][2] += av.x * bv.z; acc[0][3] += av.x * bv.w;             \
            acc[1][0] += av.y * bv.x; acc[1][1] += av.y * bv.y;             \
            acc[1][2] += av.y * bv.z; acc[1][3] += av.y * bv.w;             \
            acc[2][0] += av.z * bv.x; acc[2][1] += av.z * bv.y;             \
            acc[2][2] += av.z * bv.z; acc[2][3] += av.z * bv.w;             \
            acc[3][0] += av.w * bv.x; acc[3][1] += av.w * bv.y;             \
            acc[3][2] += av.w * bv.z; acc[3][3] += av.w * bv.w; }
        if (kc == KC) {
#pragma unroll 8
            for (int k = 0; k < KC; ++k) GEMM_STEP(k)
        } else {
            for (int k = 0; k < kc; ++k) GEMM_STEP(k)
        }
#undef GEMM_STEP
        __syncthreads();
    }
    float bvals[4];
#pragma unroll
    for (int j = 0; j < 4; ++j) bvals[j] = bias[tx * 4 + j];
#pragma unroll
    for (int i = 0; i < 4; ++i) {
        const int pix = p0 + ty * 4 + i;
        bf16x4 o;
        o.x = __float2bfloat16(mish_f(acc[i][0] + bvals[0]));
        o.y = __float2bfloat16(mish_f(acc[i][1] + bvals[1]));
        o.z = __float2bfloat16(mish_f(acc[i][2] + bvals[2]));
        o.w = __float2bfloat16(mish_f(acc[i][3] + bvals[3]));
        *(bf16x4*)&out[(size_t)pix * COUT + tx * 4] = o;
    }
}

// ---------------------------------------------------------------------------
// Kernel 6: BN (inference, moving stats) + 3x3 flow conv (16->2) + scale
// ---------------------------------------------------------------------------
__global__ __launch_bounds__(256) void bn_flow_kernel(
    const __hip_bfloat16* __restrict__ xin, const float* __restrict__ gamma,
    const float* __restrict__ beta, const float* __restrict__ mean,
    const float* __restrict__ var, const float* __restrict__ fw,
    float* __restrict__ out)
{
    const int pix = blockIdx.x * 256 + threadIdx.x;
    const int wq  = pix % WW;
    const int hq  = (pix / WW) % HH;
    const int bq  = pix / (WW * HH);
    float sc[16], sh[16];
#pragma unroll
    for (int c = 0; c < 16; ++c) {
        const float s = gamma[c] * rsqrtf(var[c] + 1e-3f);
        sc[c] = s;
        sh[c] = beta[c] - mean[c] * s;
    }
    float a0 = 0.f, a1 = 0.f;
#pragma unroll
    for (int dy = -1; dy <= 1; ++dy) {
        const int yy = hq + dy;
        if ((unsigned)yy >= HH) continue;
#pragma unroll
        for (int dx = -1; dx <= 1; ++dx) {
            const int xx = wq + dx;
            if ((unsigned)xx >= WW) continue;
            const __hip_bfloat16* px = &xin[(((size_t)bq * HH + yy) * WW + xx) * 16];
            const float* wp = &fw[((dy + 1) * 3 + (dx + 1)) * 32];
#pragma unroll
            for (int c = 0; c < 16; ++c) {
                const float v = __bfloat162float(px[c]) * sc[c] + sh[c];
                a0 += v * wp[c * 2 + 0];
                a1 += v * wp[c * 2 + 1];
            }
        }
    }
    const float SC = sqrtf((float)(HH * HH + WW * WW)); // 192*sqrt(2)
    out[(size_t)pix * 2 + 0] = SC * a0;
    out[(size_t)pix * 2 + 1] = SC * a1;
}

// ---------------------------------------------------------------------------
// Workspace plan (bf16 elements; peak 123.3 MB):
//   x0cv = ws[0 : N*81]                 cost volume
//   t1   = ws[N*81 : N*81+N*128]        sepconv0 out
//   t2   = alias x0cv (dead after sepconv0->1), 64 ch
//   t3   = alias t1 (dead after sepconv1->2), 32 ch
//   t4   = ws[N*64 : N*80] inside x0cv region (t2 uses first 64 ch worth)
// ---------------------------------------------------------------------------
extern "C" void kernel_launch(void* const* d_in, const int* in_sizes, int n_in,
                              void* d_out, int out_size, void* d_ws, size_t ws_size,
                              hipStream_t stream)
{
    const float* prv   = (const float*)d_in[0];
    const float* nxt   = (const float*)d_in[1];
    const float* dw0   = (const float*)d_in[2];
    const float* pw0   = (const float*)d_in[3];
    const float* b0    = (const float*)d_in[4];
    const float* dw1   = (const float*)d_in[5];
    const float* pw1   = (const float*)d_in[6];
    const float* b1    = (const float*)d_in[7];
    const float* dw2   = (const float*)d_in[8];
    const float* pw2   = (const float*)d_in[9];
    const float* b2    = (const float*)d_in[10];
    const float* dw3   = (const float*)d_in[11];
    const float* pw3   = (const float*)d_in[12];
    const float* b3    = (const float*)d_in[13];
    const float* bn_g  = (const float*)d_in[14];
    const float* bn_b  = (const float*)d_in[15];
    const float* bn_m  = (const float*)d_in[16];
    const float* bn_v  = (const float*)d_in[17];
    const float* fw    = (const float*)d_in[18];
    float* outp = (float*)d_out;

    const size_t N = (size_t)NPIX;
    __hip_bfloat16* ws = (__hip_bfloat16*)d_ws;
    __hip_bfloat16* x0cv = ws;              // [N, 81]
    __hip_bfloat16* t1   = ws + N * NCV;    // [N, 128]
    __hip_bfloat16* t2   = ws;              // [N, 64]  (aliases x0cv)
    __hip_bfloat16* t3   = t1;              // [N, 32]  (aliases t1)
    __hip_bfloat16* t4   = ws + N * 64;     // [N, 16]  (tail of x0cv region)

    cost_kernel<<<dim3(HH, BB), 192, 0, stream>>>(prv, nxt, x0cv);
    sepconv_kernel<209, 128, 1><<<NPIX / 32,  256, 0, stream>>>(x0cv, prv, nxt, dw0, pw0, b0, t1);
    sepconv_kernel<128, 64,  0><<<NPIX / 64,  256, 0, stream>>>(t1, nullptr, nullptr, dw1, pw1, b1, t2);
    sepconv_kernel<64,  32,  0><<<NPIX / 128, 256, 0, stream>>>(t2, nullptr, nullptr, dw2, pw2, b2, t3);
    sepconv_kernel<32,  16,  0><<<NPIX / 256, 256, 0, stream>>>(t3, nullptr, nullptr, dw3, pw3, b3, t4);
    bn_flow_kernel<<<NPIX / 256, 256, 0, stream>>>(t4, bn_g, bn_b, bn_m, bn_v, fw, outp);
}

// Round 3
// 1050.274 us; speedup vs baseline: 2.0270x; 2.0270x over previous
//
#include <hip/hip_runtime.h>
#include <hip/hip_bf16.h>

// Problem constants
#define BB 8
#define HH 192
#define WW 192
#define CC0 64
#define NPIX (BB*HH*WW) // 294912
#define NCV 81
#define CVP 96          // cv padded channels (16B-aligned rows)

typedef __attribute__((ext_vector_type(8))) short short8;
typedef __attribute__((ext_vector_type(4))) float f32x4;

__device__ __forceinline__ float bf2f(short s) {
    union { unsigned u; float f; } x; x.u = ((unsigned)(unsigned short)s) << 16; return x.f;
}
__device__ __forceinline__ short f2bf(float f) {
    __hip_bfloat16 h = __float2bfloat16(f);
    return *reinterpret_cast<short*>(&h);
}

__device__ __forceinline__ float mish_f(float v) {
    if (v > 20.0f) return v;
    const float u = __expf(v);
    const float n = u * (u + 2.0f);
    return v * n / (n + 2.0f);
}

// ---------------------------------------------------------------------------
// Weight prep: bf16-convert + permute + pad all dw/pw weights into ws.
// Virtual channel order for stage0: [prv 0-63][nxt 64-127][cv 128-208][pad].
// dwbf_s: [9][Kpad]; Bt_s: [COUT][Kpad] (k-contiguous rows for b128 frags).
// ---------------------------------------------------------------------------
__global__ __launch_bounds__(256) void prep_kernel(
    const float* __restrict__ dw0, const float* __restrict__ pw0,
    const float* __restrict__ dw1, const float* __restrict__ pw1,
    const float* __restrict__ dw2, const float* __restrict__ pw2,
    const float* __restrict__ dw3, const float* __restrict__ pw3,
    __hip_bfloat16* __restrict__ wout)
{
    const int u = blockIdx.x * 256 + threadIdx.x;
    if (u >= 43456) return;
    float v = 0.f;
    if (u < 2016) {                     // dwbf0 [9][224]
        const int t = u / 224, c = u % 224;
        if (c < 64)       v = dw0[t*209 + 81  + c];
        else if (c < 128) v = dw0[t*209 + 145 + (c-64)];
        else if (c < 209) v = dw0[t*209 + (c-128)];
    } else if (u < 3168) {              // dwbf1 [9][128]
        const int r = u-2016, t = r/128, c = r%128; v = dw1[t*128+c];
    } else if (u < 3744) {              // dwbf2 [9][64]
        const int r = u-3168, t = r/64, c = r%64; v = dw2[t*64+c];
    } else if (u < 4032) {              // dwbf3 [9][32]
        const int r = u-3744, t = r/32, c = r%32; v = dw3[t*32+c];
    } else if (u < 32704) {             // Bt0 [128][224]
        const int r = u-4032, n = r/224, c = r%224;
        if (c < 64)       v = pw0[(81+c)*128 + n];
        else if (c < 128) v = pw0[(145+(c-64))*128 + n];
        else if (c < 209) v = pw0[(c-128)*128 + n];
    } else if (u < 40896) {             // Bt1 [64][128]
        const int r = u-32704, n = r/128, c = r%128; v = pw1[c*64 + n];
    } else if (u < 42944) {             // Bt2 [32][64]
        const int r = u-40896, n = r/64, c = r%64; v = pw2[c*32 + n];
    } else {                            // Bt3 [16][32]
        const int r = u-42944, n = r/32, c = r%32; v = pw3[c*16 + n];
    }
    wout[u] = __float2bfloat16(v);
}

// ---------------------------------------------------------------------------
// Cost volume (unchanged structure from R1, passed): out [N][96] bf16, pad 81-95=0
// ---------------------------------------------------------------------------
__global__ __launch_bounds__(192) void cost_kernel(
    const float* __restrict__ prv, const float* __restrict__ nxt,
    __hip_bfloat16* __restrict__ cv)
{
    const int w = threadIdx.x;
    const int h = blockIdx.x;
    const int b = blockIdx.y;
    __shared__ float4 srow[200 * 17];

    const size_t pixbase = ((size_t)b * HH + h) * WW + w;
    const float* pptr = prv + pixbase * CC0;
    float4 p[16];
#pragma unroll
    for (int cc = 0; cc < 16; ++cc) p[cc] = *(const float4*)(pptr + cc * 4);

    const size_t obase = pixbase * CVP;

    for (int r = 0; r < 9; ++r) {
        __syncthreads();
        const int y = h - 4 + r;
        const bool yok = ((unsigned)y < HH);
        const float* rowp = nxt + (((size_t)b * HH + y) * WW) * CC0;
        for (int idx = w; idx < 200 * 16; idx += 192) {
            const int col = idx >> 4;
            const int cc  = idx & 15;
            const int x   = col - 4;
            float4 v = make_float4(0.f, 0.f, 0.f, 0.f);
            if (yok && (unsigned)x < WW)
                v = *(const float4*)(rowp + (size_t)x * CC0 + cc * 4);
            srow[col * 17 + cc] = v;
        }
        __syncthreads();
#pragma unroll
        for (int dj = 0; dj < 9; ++dj) {
            const float4* sp = &srow[(w + dj) * 17];
            float s = 0.f;
#pragma unroll
            for (int cc = 0; cc < 16; ++cc) {
                const float4 nv = sp[cc];
                s += p[cc].x * nv.x; s += p[cc].y * nv.y;
                s += p[cc].z * nv.z; s += p[cc].w * nv.w;
            }
            const float m = s * (1.0f / 64.0f);
            cv[obase + r * 9 + dj] = __float2bfloat16((m > 0.f) ? m : 0.1f * m);
        }
    }
#pragma unroll
    for (int c = NCV; c < CVP; ++c) cv[obase + c] = __float2bfloat16(0.f);
}

// ---------------------------------------------------------------------------
// Fused sepconv: dw3x3 (LDS halo tile) -> bf16 MFMA pointwise -> bias+mish.
// Block = 32w x 4h pixel tile (M=128), K-loop in 32-chunks, 4 waves.
// MODE 1: stage0 virtual input [prv|nxt|cv] (chunk-uniform source).
// sA/sB use XOR swizzle px^(kb<<2) -> conflict-free b128 reads & ~2-way writes.
// ---------------------------------------------------------------------------
template<int KP, int COUT, int MODE>
__global__ __launch_bounds__(256) void sepconv_mfma(
    const __hip_bfloat16* __restrict__ in,
    const float* __restrict__ prv, const float* __restrict__ nxt,
    const __hip_bfloat16* __restrict__ dwbf,   // [9][KP]
    const __hip_bfloat16* __restrict__ Bt,     // [COUT][KP]
    const float* __restrict__ bias,
    __hip_bfloat16* __restrict__ out)
{
    constexpr int NT  = COUT / 16;
    constexpr int WGN = (NT >= 2) ? 2 : 1;
    constexpr int WGM = 4 / WGN;
    constexpr int TM  = 8 / WGM;
    constexpr int TN  = NT / WGN;

    __shared__ __align__(16) short sIn[6][34][32];
    __shared__ __align__(16) short sA[4][128][8];
    __shared__ __align__(16) short sB[4][COUT][8];
    __shared__ __align__(16) short sW[9][32];

    const int tid  = threadIdx.x;
    const int lane = tid & 63;
    const int wv   = tid >> 6;
    const int ln15 = lane & 15;
    const int kq   = lane >> 4;
    const int wm   = wv % WGM;
    const int wn   = wv / WGM;

    const int bx = blockIdx.x;
    const int tw = bx % 6;
    const int th = (bx / 6) % 48;
    const int bb = bx / 288;
    const int w0 = tw * 32, h0 = th * 4;

    // depthwise thread mapping: vertical px-pair, one 8ch-vec
    const int dkb = tid & 3;
    const int pxg = tid >> 2;        // 0..63
    const int dww = pxg & 31;
    const int dhh = (pxg >> 5) * 2;  // 0 or 2

    f32x4 acc[TM][TN] = {};

    for (int k0 = 0; k0 < KP; k0 += 32) {
        // --- stage input halo tile (34x6 px, 32 ch) ---
        for (int u = tid; u < 816; u += 256) {
            const int kb = u & 3;
            const int p  = u >> 2;
            const int iw = p % 34, ih = p / 34;
            const int gw = w0 - 1 + iw, gh = h0 - 1 + ih;
            short8 v = {0,0,0,0,0,0,0,0};
            if ((unsigned)gw < (unsigned)WW && (unsigned)gh < (unsigned)HH) {
                const size_t pix = ((size_t)bb * HH + gh) * WW + gw;
                const int c0 = k0 + kb * 8;
                if (MODE == 0) {
                    v = *(const short8*)((const short*)in + pix * KP + c0);
                } else {
                    if (c0 < 64) {
                        const float4* s = (const float4*)(prv + pix * 64 + c0);
                        const float4 a = s[0], bq = s[1];
                        v[0]=f2bf(a.x);  v[1]=f2bf(a.y);  v[2]=f2bf(a.z);  v[3]=f2bf(a.w);
                        v[4]=f2bf(bq.x); v[5]=f2bf(bq.y); v[6]=f2bf(bq.z); v[7]=f2bf(bq.w);
                    } else if (c0 < 128) {
                        const float4* s = (const float4*)(nxt + pix * 64 + (c0 - 64));
                        const float4 a = s[0], bq = s[1];
                        v[0]=f2bf(a.x);  v[1]=f2bf(a.y);  v[2]=f2bf(a.z);  v[3]=f2bf(a.w);
                        v[4]=f2bf(bq.x); v[5]=f2bf(bq.y); v[6]=f2bf(bq.z); v[7]=f2bf(bq.w);
                    } else {
                        v = *(const short8*)((const short*)in + pix * CVP + (c0 - 128));
                    }
                }
            }
            *(short8*)&sIn[ih][iw][kb * 8] = v;
        }
        // --- stage dw weights chunk ---
        if (tid < 36) {
            const int t = tid >> 2, kb = tid & 3;
            *(short8*)&sW[t][kb * 8] =
                *(const short8*)((const short*)dwbf + t * KP + k0 + kb * 8);
        }
        // --- stage Bt chunk ---
        for (int u = tid; u < COUT * 4; u += 256) {
            const int n = u >> 2, kb = u & 3;
            short8 v = *(const short8*)((const short*)Bt + (size_t)n * KP + k0 + kb * 8);
            *(short8*)&sB[kb][n ^ (kb << 2)][0] = v;
        }
        __syncthreads();

        // --- depthwise: 2 vertically-adjacent px, 8 ch ---
        {
            short8 wv8[9];
#pragma unroll
            for (int t = 0; t < 9; ++t) wv8[t] = *(const short8*)&sW[t][dkb * 8];
            float r0[8] = {0,0,0,0,0,0,0,0};
            float r1[8] = {0,0,0,0,0,0,0,0};
#pragma unroll
            for (int dy = 0; dy < 4; ++dy) {
#pragma unroll
                for (int dx = 0; dx < 3; ++dx) {
                    const short8 iv = *(const short8*)&sIn[dhh + dy][dww + dx][dkb * 8];
                    float fv[8];
#pragma unroll
                    for (int j = 0; j < 8; ++j) fv[j] = bf2f(iv[j]);
                    if (dy < 3) {
                        const short8 w8 = wv8[dy * 3 + dx];
#pragma unroll
                        for (int j = 0; j < 8; ++j) r0[j] += fv[j] * bf2f(w8[j]);
                    }
                    if (dy >= 1) {
                        const short8 w8 = wv8[(dy - 1) * 3 + dx];
#pragma unroll
                        for (int j = 0; j < 8; ++j) r1[j] += fv[j] * bf2f(w8[j]);
                    }
                }
            }
            const int px0 = dhh * 32 + dww;
            short8 o0, o1;
#pragma unroll
            for (int j = 0; j < 8; ++j) { o0[j] = f2bf(r0[j]); o1[j] = f2bf(r1[j]); }
            *(short8*)&sA[dkb][px0 ^ (dkb << 2)][0] = o0;
            *(short8*)&sA[dkb][(px0 + 32) ^ (dkb << 2)][0] = o1;
        }
        __syncthreads();

        // --- MFMA: A[m][k] x B[k][n] ---
        short8 af[TM], bf8[TN];
#pragma unroll
        for (int i = 0; i < TM; ++i) {
            const int m = (wm * TM + i) * 16 + ln15;
            af[i] = *(const short8*)&sA[kq][m ^ (kq << 2)][0];
        }
#pragma unroll
        for (int j = 0; j < TN; ++j) {
            const int n = (wn * TN + j) * 16 + ln15;
            bf8[j] = *(const short8*)&sB[kq][n ^ (kq << 2)][0];
        }
#pragma unroll
        for (int i = 0; i < TM; ++i)
#pragma unroll
            for (int j = 0; j < TN; ++j)
                acc[i][j] = __builtin_amdgcn_mfma_f32_16x16x32_bf16(
                    af[i], bf8[j], acc[i][j], 0, 0, 0);
        __syncthreads();
    }

    // --- epilogue: bias + mish + bf16 store (C: col=lane&15, row=(lane>>4)*4+r) ---
#pragma unroll
    for (int j = 0; j < TN; ++j) {
        const int n = (wn * TN + j) * 16 + ln15;
        const float bj = bias[n];
#pragma unroll
        for (int i = 0; i < TM; ++i) {
#pragma unroll
            for (int r = 0; r < 4; ++r) {
                const int m  = (wm * TM + i) * 16 + kq * 4 + r;
                const int gh = h0 + (m >> 5), gw = w0 + (m & 31);
                const size_t gp = ((size_t)bb * HH + gh) * WW + gw;
                out[gp * COUT + n] = __float2bfloat16(mish_f(acc[i][j][r] + bj));
            }
        }
    }
}

// ---------------------------------------------------------------------------
// BN + 3x3 flow conv (16->2) + scale
// ---------------------------------------------------------------------------
__global__ __launch_bounds__(256) void bn_flow_kernel(
    const __hip_bfloat16* __restrict__ xin, const float* __restrict__ gamma,
    const float* __restrict__ beta, const float* __restrict__ mean,
    const float* __restrict__ var, const float* __restrict__ fw,
    float* __restrict__ out)
{
    const int pix = blockIdx.x * 256 + threadIdx.x;
    const int wq  = pix % WW;
    const int hq  = (pix / WW) % HH;
    const int bq  = pix / (WW * HH);
    float sc[16], sh[16];
#pragma unroll
    for (int c = 0; c < 16; ++c) {
        const float s = gamma[c] * rsqrtf(var[c] + 1e-3f);
        sc[c] = s;
        sh[c] = beta[c] - mean[c] * s;
    }
    float a0 = 0.f, a1 = 0.f;
#pragma unroll
    for (int dy = -1; dy <= 1; ++dy) {
        const int yy = hq + dy;
        if ((unsigned)yy >= HH) continue;
#pragma unroll
        for (int dx = -1; dx <= 1; ++dx) {
            const int xx = wq + dx;
            if ((unsigned)xx >= WW) continue;
            const __hip_bfloat16* px = &xin[(((size_t)bq * HH + yy) * WW + xx) * 16];
            const float* wp = &fw[((dy + 1) * 3 + (dx + 1)) * 32];
#pragma unroll
            for (int c = 0; c < 16; ++c) {
                const float v = __bfloat162float(px[c]) * sc[c] + sh[c];
                a0 += v * wp[c * 2 + 0];
                a1 += v * wp[c * 2 + 1];
            }
        }
    }
    const float SC = sqrtf((float)(HH * HH + WW * WW));
    out[(size_t)pix * 2 + 0] = SC * a0;
    out[(size_t)pix * 2 + 1] = SC * a1;
}

// ---------------------------------------------------------------------------
// Workspace (bf16 elements), peak 132.2 MB:
//   cv [N*96] | t1 [N*128] | weights [43456]
//   t2 aliases cv[0:N*64], t4 = cv[N*64:N*80], t3 aliases t1[0:N*32]
// ---------------------------------------------------------------------------
extern "C" void kernel_launch(void* const* d_in, const int* in_sizes, int n_in,
                              void* d_out, int out_size, void* d_ws, size_t ws_size,
                              hipStream_t stream)
{
    const float* prv   = (const float*)d_in[0];
    const float* nxt   = (const float*)d_in[1];
    const float* dw0   = (const float*)d_in[2];
    const float* pw0   = (const float*)d_in[3];
    const float* b0    = (const float*)d_in[4];
    const float* dw1   = (const float*)d_in[5];
    const float* pw1   = (const float*)d_in[6];
    const float* b1    = (const float*)d_in[7];
    const float* dw2   = (const float*)d_in[8];
    const float* pw2   = (const float*)d_in[9];
    const float* b2    = (const float*)d_in[10];
    const float* dw3   = (const float*)d_in[11];
    const float* pw3   = (const float*)d_in[12];
    const float* b3    = (const float*)d_in[13];
    const float* bn_g  = (const float*)d_in[14];
    const float* bn_b  = (const float*)d_in[15];
    const float* bn_m  = (const float*)d_in[16];
    const float* bn_v  = (const float*)d_in[17];
    const float* fw    = (const float*)d_in[18];
    float* outp = (float*)d_out;

    const size_t N = (size_t)NPIX;
    __hip_bfloat16* ws  = (__hip_bfloat16*)d_ws;
    __hip_bfloat16* cv  = ws;                    // [N][96]
    __hip_bfloat16* t1  = ws + N * 96;           // [N][128]
    __hip_bfloat16* t2  = ws;                    // [N][64]  alias cv
    __hip_bfloat16* t3  = t1;                    // [N][32]  alias t1
    __hip_bfloat16* t4  = ws + N * 64;           // [N][16]  tail of cv region
    __hip_bfloat16* wts = ws + N * 224;          // 43456 elements
    __hip_bfloat16* dwbf0 = wts;
    __hip_bfloat16* dwbf1 = wts + 2016;
    __hip_bfloat16* dwbf2 = wts + 3168;
    __hip_bfloat16* dwbf3 = wts + 3744;
    __hip_bfloat16* Bt0   = wts + 4032;
    __hip_bfloat16* Bt1   = wts + 32704;
    __hip_bfloat16* Bt2   = wts + 40896;
    __hip_bfloat16* Bt3   = wts + 42944;

    prep_kernel<<<170, 256, 0, stream>>>(dw0, pw0, dw1, pw1, dw2, pw2, dw3, pw3, wts);
    cost_kernel<<<dim3(HH, BB), 192, 0, stream>>>(prv, nxt, cv);
    sepconv_mfma<224, 128, 1><<<2304, 256, 0, stream>>>(cv, prv, nxt, dwbf0, Bt0, b0, t1);
    sepconv_mfma<128,  64, 0><<<2304, 256, 0, stream>>>(t1, nullptr, nullptr, dwbf1, Bt1, b1, t2);
    sepconv_mfma< 64,  32, 0><<<2304, 256, 0, stream>>>(t2, nullptr, nullptr, dwbf2, Bt2, b2, t3);
    sepconv_mfma< 32,  16, 0><<<2304, 256, 0, stream>>>(t3, nullptr, nullptr, dwbf3, Bt3, b3, t4);
    bn_flow_kernel<<<NPIX / 256, 256, 0, stream>>>(t4, bn_g, bn_b, bn_m, bn_v, fw, outp);
}

// Round 4
// 565.572 us; speedup vs baseline: 3.7641x; 1.8570x over previous
//
#include <hip/hip_runtime.h>
#include <hip/hip_bf16.h>

// Problem constants
#define BB 8
#define HH 192
#define WW 192
#define CC0 64
#define NPIX (BB*HH*WW) // 294912
#define NCV 81
#define CVP 96          // cv padded channels (16B-aligned rows)

typedef __attribute__((ext_vector_type(8))) short short8;
typedef __attribute__((ext_vector_type(4))) short short4v;
typedef __attribute__((ext_vector_type(4))) float f32x4;

__device__ __forceinline__ float bf2f(short s) {
    union { unsigned u; float f; } x; x.u = ((unsigned)(unsigned short)s) << 16; return x.f;
}
__device__ __forceinline__ short f2bf(float f) {
    __hip_bfloat16 h = __float2bfloat16(f);
    return *reinterpret_cast<short*>(&h);
}

__device__ __forceinline__ float mish_f(float v) {
    if (v > 20.0f) return v;
    const float u = __expf(v);
    const float n = u * (u + 2.0f);
    return v * n / (n + 2.0f);
}

// ---------------------------------------------------------------------------
// Weight prep (unchanged from R2): bf16 convert + permute + pad into ws.
// ---------------------------------------------------------------------------
__global__ __launch_bounds__(256) void prep_kernel(
    const float* __restrict__ dw0, const float* __restrict__ pw0,
    const float* __restrict__ dw1, const float* __restrict__ pw1,
    const float* __restrict__ dw2, const float* __restrict__ pw2,
    const float* __restrict__ dw3, const float* __restrict__ pw3,
    __hip_bfloat16* __restrict__ wout)
{
    const int u = blockIdx.x * 256 + threadIdx.x;
    if (u >= 43456) return;
    float v = 0.f;
    if (u < 2016) {                     // dwbf0 [9][224]
        const int t = u / 224, c = u % 224;
        if (c < 64)       v = dw0[t*209 + 81  + c];
        else if (c < 128) v = dw0[t*209 + 145 + (c-64)];
        else if (c < 209) v = dw0[t*209 + (c-128)];
    } else if (u < 3168) {              // dwbf1 [9][128]
        const int r = u-2016, t = r/128, c = r%128; v = dw1[t*128+c];
    } else if (u < 3744) {              // dwbf2 [9][64]
        const int r = u-3168, t = r/64, c = r%64; v = dw2[t*64+c];
    } else if (u < 4032) {              // dwbf3 [9][32]
        const int r = u-3744, t = r/32, c = r%32; v = dw3[t*32+c];
    } else if (u < 32704) {             // Bt0 [128][224]
        const int r = u-4032, n = r/224, c = r%224;
        if (c < 64)       v = pw0[(81+c)*128 + n];
        else if (c < 128) v = pw0[(145+(c-64))*128 + n];
        else if (c < 209) v = pw0[(c-128)*128 + n];
    } else if (u < 40896) {             // Bt1 [64][128]
        const int r = u-32704, n = r/128, c = r%128; v = pw1[c*64 + n];
    } else if (u < 42944) {             // Bt2 [32][64]
        const int r = u-40896, n = r/64, c = r%64; v = pw2[c*32 + n];
    } else {                            // Bt3 [16][32]
        const int r = u-42944, n = r/32, c = r%32; v = pw3[c*16 + n];
    }
    wout[u] = __float2bfloat16(v);
}

// ---------------------------------------------------------------------------
// Cost volume via MFMA banded QK^T.
// Block = 64 output px of one (b,h) row; 4 waves, one 16-px tile per wave.
// A (prv frags) in registers; per y-offset r: stage nxt row slice [80px][64ch]
// as bf16 in LDS (stride 70 for bank spread), S[16][32] = 2 N-tiles x 2 K-half
// MFMAs, scatter band dj=n-m in [0,8] (x1/64, leaky 0.1) into LDS cv tile,
// coalesced bf16 store at end. OOB rows/cols contribute exact zeros.
// ---------------------------------------------------------------------------
__global__ __launch_bounds__(256) void cost_mfma_kernel(
    const float* __restrict__ prv, const float* __restrict__ nxt,
    __hip_bfloat16* __restrict__ cv)
{
    __shared__ __align__(16) short sNxt[80][70];
    __shared__ __align__(16) short sCv[64][96];

    const int tid  = threadIdx.x;
    const int lane = tid & 63;
    const int wv   = tid >> 6;
    const int ln15 = lane & 15;
    const int kq   = lane >> 4;

    const int bx = blockIdx.x;
    const int tw = bx % 3;
    const int h  = (bx / 3) % HH;
    const int b  = bx / (3 * HH);
    const int w0 = tw * 64;

    // zero-init sCv (covers pad channels 81..95 and OOB-row channels)
    {
        const short8 z = {0,0,0,0,0,0,0,0};
        for (int t = 0; t < 3; ++t) {
            const int idx = tid + t * 256;     // 0..767
            const int px = idx / 12, c8 = idx % 12;
            *(short8*)&sCv[px][c8 * 8] = z;
        }
    }

    // A fragments: prv[w0 + wv*16 + ln15][ch], k-half 0: ch kq*8..+7, half 1: +32
    short8 af0, af1;
    {
        const int apx = w0 + wv * 16 + ln15;
        const float* ap = prv + (((size_t)b * HH + h) * WW + apx) * CC0 + kq * 8;
        const float4 x0 = *(const float4*)(ap);
        const float4 x1 = *(const float4*)(ap + 4);
        const float4 x2 = *(const float4*)(ap + 32);
        const float4 x3 = *(const float4*)(ap + 36);
        af0[0]=f2bf(x0.x); af0[1]=f2bf(x0.y); af0[2]=f2bf(x0.z); af0[3]=f2bf(x0.w);
        af0[4]=f2bf(x1.x); af0[5]=f2bf(x1.y); af0[6]=f2bf(x1.z); af0[7]=f2bf(x1.w);
        af1[0]=f2bf(x2.x); af1[1]=f2bf(x2.y); af1[2]=f2bf(x2.z); af1[3]=f2bf(x2.w);
        af1[4]=f2bf(x3.x); af1[5]=f2bf(x3.y); af1[6]=f2bf(x3.z); af1[7]=f2bf(x3.w);
    }

    const int m0 = wv * 16;

    for (int r = 0; r < 9; ++r) {
        const int y = h - 4 + r;
        const bool yok = ((unsigned)y < (unsigned)HH);
        __syncthreads();   // protect previous iteration's sNxt reads
        if (yok) {
            const float* rowp = nxt + (((size_t)b * HH + y) * WW) * CC0;
#pragma unroll
            for (int t = 0; t < 5; ++t) {
                const int idx = tid + t * 256;   // 0..1279
                const int px  = idx >> 4;        // 0..79  (global w = w0-4+px)
                const int c4  = idx & 15;
                const int gw  = w0 - 4 + px;
                float4 v = make_float4(0.f, 0.f, 0.f, 0.f);
                if ((unsigned)gw < (unsigned)WW)
                    v = *(const float4*)(rowp + (size_t)gw * CC0 + c4 * 4);
                short4v sv;
                sv[0]=f2bf(v.x); sv[1]=f2bf(v.y); sv[2]=f2bf(v.z); sv[3]=f2bf(v.w);
                *(short4v*)&sNxt[px][c4 * 4] = sv;
            }
        }
        __syncthreads();
        if (!yok) continue;

#pragma unroll
        for (int j = 0; j < 2; ++j) {
            // B frag: n = j*16+ln15 -> staged px idx = m0 + n; value nxt[n_px][k]
            const short* bp = &sNxt[m0 + j * 16 + ln15][kq * 8];
            const short8 b0 = *(const short8*)bp;
            const short8 b1 = *(const short8*)(bp + 32);
            f32x4 acc = {0.f, 0.f, 0.f, 0.f};
            acc = __builtin_amdgcn_mfma_f32_16x16x32_bf16(af0, b0, acc, 0, 0, 0);
            acc = __builtin_amdgcn_mfma_f32_16x16x32_bf16(af1, b1, acc, 0, 0, 0);
            // scatter valid band: C elem (m = kq*4+rr, n = j*16+ln15), dj = n-m
#pragma unroll
            for (int rr = 0; rr < 4; ++rr) {
                const int m  = kq * 4 + rr;
                const int dj = j * 16 + ln15 - m;
                if ((unsigned)dj < 9u) {
                    float mv = acc[rr] * (1.0f / 64.0f);
                    mv = (mv > 0.f) ? mv : 0.1f * mv;
                    sCv[m0 + m][r * 9 + dj] = f2bf(mv);
                }
            }
        }
    }

    __syncthreads();
    // coalesced store: 64 px x 96 ch bf16
    short* outp = (short*)cv + (((size_t)b * HH + h) * WW + w0) * CVP;
#pragma unroll
    for (int t = 0; t < 3; ++t) {
        const int idx = tid + t * 256;
        const int px = idx / 12, c8 = idx % 12;
        *(short8*)(outp + (size_t)px * CVP + c8 * 8) = *(const short8*)&sCv[px][c8 * 8];
    }
}

// ---------------------------------------------------------------------------
// Fused sepconv (unchanged from R2, passed): dw3x3 -> bf16 MFMA -> bias+mish
// ---------------------------------------------------------------------------
template<int KP, int COUT, int MODE>
__global__ __launch_bounds__(256) void sepconv_mfma(
    const __hip_bfloat16* __restrict__ in,
    const float* __restrict__ prv, const float* __restrict__ nxt,
    const __hip_bfloat16* __restrict__ dwbf,   // [9][KP]
    const __hip_bfloat16* __restrict__ Bt,     // [COUT][KP]
    const float* __restrict__ bias,
    __hip_bfloat16* __restrict__ out)
{
    constexpr int NT  = COUT / 16;
    constexpr int WGN = (NT >= 2) ? 2 : 1;
    constexpr int WGM = 4 / WGN;
    constexpr int TM  = 8 / WGM;
    constexpr int TN  = NT / WGN;

    __shared__ __align__(16) short sIn[6][34][32];
    __shared__ __align__(16) short sA[4][128][8];
    __shared__ __align__(16) short sB[4][COUT][8];
    __shared__ __align__(16) short sW[9][32];

    const int tid  = threadIdx.x;
    const int lane = tid & 63;
    const int wv   = tid >> 6;
    const int ln15 = lane & 15;
    const int kq   = lane >> 4;
    const int wm   = wv % WGM;
    const int wn   = wv / WGM;

    const int bx = blockIdx.x;
    const int tw = bx % 6;
    const int th = (bx / 6) % 48;
    const int bb = bx / 288;
    const int w0 = tw * 32, h0 = th * 4;

    const int dkb = tid & 3;
    const int pxg = tid >> 2;
    const int dww = pxg & 31;
    const int dhh = (pxg >> 5) * 2;

    f32x4 acc[TM][TN] = {};

    for (int k0 = 0; k0 < KP; k0 += 32) {
        for (int u = tid; u < 816; u += 256) {
            const int kb = u & 3;
            const int p  = u >> 2;
            const int iw = p % 34, ih = p / 34;
            const int gw = w0 - 1 + iw, gh = h0 - 1 + ih;
            short8 v = {0,0,0,0,0,0,0,0};
            if ((unsigned)gw < (unsigned)WW && (unsigned)gh < (unsigned)HH) {
                const size_t pix = ((size_t)bb * HH + gh) * WW + gw;
                const int c0 = k0 + kb * 8;
                if (MODE == 0) {
                    v = *(const short8*)((const short*)in + pix * KP + c0);
                } else {
                    if (c0 < 64) {
                        const float4* s = (const float4*)(prv + pix * 64 + c0);
                        const float4 a = s[0], bq = s[1];
                        v[0]=f2bf(a.x);  v[1]=f2bf(a.y);  v[2]=f2bf(a.z);  v[3]=f2bf(a.w);
                        v[4]=f2bf(bq.x); v[5]=f2bf(bq.y); v[6]=f2bf(bq.z); v[7]=f2bf(bq.w);
                    } else if (c0 < 128) {
                        const float4* s = (const float4*)(nxt + pix * 64 + (c0 - 64));
                        const float4 a = s[0], bq = s[1];
                        v[0]=f2bf(a.x);  v[1]=f2bf(a.y);  v[2]=f2bf(a.z);  v[3]=f2bf(a.w);
                        v[4]=f2bf(bq.x); v[5]=f2bf(bq.y); v[6]=f2bf(bq.z); v[7]=f2bf(bq.w);
                    } else {
                        v = *(const short8*)((const short*)in + pix * CVP + (c0 - 128));
                    }
                }
            }
            *(short8*)&sIn[ih][iw][kb * 8] = v;
        }
        if (tid < 36) {
            const int t = tid >> 2, kb = tid & 3;
            *(short8*)&sW[t][kb * 8] =
                *(const short8*)((const short*)dwbf + t * KP + k0 + kb * 8);
        }
        for (int u = tid; u < COUT * 4; u += 256) {
            const int n = u >> 2, kb = u & 3;
            short8 v = *(const short8*)((const short*)Bt + (size_t)n * KP + k0 + kb * 8);
            *(short8*)&sB[kb][n ^ (kb << 2)][0] = v;
        }
        __syncthreads();

        {
            short8 wv8[9];
#pragma unroll
            for (int t = 0; t < 9; ++t) wv8[t] = *(const short8*)&sW[t][dkb * 8];
            float r0[8] = {0,0,0,0,0,0,0,0};
            float r1[8] = {0,0,0,0,0,0,0,0};
#pragma unroll
            for (int dy = 0; dy < 4; ++dy) {
#pragma unroll
                for (int dx = 0; dx < 3; ++dx) {
                    const short8 iv = *(const short8*)&sIn[dhh + dy][dww + dx][dkb * 8];
                    float fv[8];
#pragma unroll
                    for (int j = 0; j < 8; ++j) fv[j] = bf2f(iv[j]);
                    if (dy < 3) {
                        const short8 w8 = wv8[dy * 3 + dx];
#pragma unroll
                        for (int j = 0; j < 8; ++j) r0[j] += fv[j] * bf2f(w8[j]);
                    }
                    if (dy >= 1) {
                        const short8 w8 = wv8[(dy - 1) * 3 + dx];
#pragma unroll
                        for (int j = 0; j < 8; ++j) r1[j] += fv[j] * bf2f(w8[j]);
                    }
                }
            }
            const int px0 = dhh * 32 + dww;
            short8 o0, o1;
#pragma unroll
            for (int j = 0; j < 8; ++j) { o0[j] = f2bf(r0[j]); o1[j] = f2bf(r1[j]); }
            *(short8*)&sA[dkb][px0 ^ (dkb << 2)][0] = o0;
            *(short8*)&sA[dkb][(px0 + 32) ^ (dkb << 2)][0] = o1;
        }
        __syncthreads();

        short8 af[TM], bf8[TN];
#pragma unroll
        for (int i = 0; i < TM; ++i) {
            const int m = (wm * TM + i) * 16 + ln15;
            af[i] = *(const short8*)&sA[kq][m ^ (kq << 2)][0];
        }
#pragma unroll
        for (int j = 0; j < TN; ++j) {
            const int n = (wn * TN + j) * 16 + ln15;
            bf8[j] = *(const short8*)&sB[kq][n ^ (kq << 2)][0];
        }
#pragma unroll
        for (int i = 0; i < TM; ++i)
#pragma unroll
            for (int j = 0; j < TN; ++j)
                acc[i][j] = __builtin_amdgcn_mfma_f32_16x16x32_bf16(
                    af[i], bf8[j], acc[i][j], 0, 0, 0);
        __syncthreads();
    }

#pragma unroll
    for (int j = 0; j < TN; ++j) {
        const int n = (wn * TN + j) * 16 + ln15;
        const float bj = bias[n];
#pragma unroll
        for (int i = 0; i < TM; ++i) {
#pragma unroll
            for (int r = 0; r < 4; ++r) {
                const int m  = (wm * TM + i) * 16 + kq * 4 + r;
                const int gh = h0 + (m >> 5), gw = w0 + (m & 31);
                const size_t gp = ((size_t)bb * HH + gh) * WW + gw;
                out[gp * COUT + n] = __float2bfloat16(mish_f(acc[i][j][r] + bj));
            }
        }
    }
}

// ---------------------------------------------------------------------------
// BN + 3x3 flow conv (16->2) + scale (unchanged)
// ---------------------------------------------------------------------------
__global__ __launch_bounds__(256) void bn_flow_kernel(
    const __hip_bfloat16* __restrict__ xin, const float* __restrict__ gamma,
    const float* __restrict__ beta, const float* __restrict__ mean,
    const float* __restrict__ var, const float* __restrict__ fw,
    float* __restrict__ out)
{
    const int pix = blockIdx.x * 256 + threadIdx.x;
    const int wq  = pix % WW;
    const int hq  = (pix / WW) % HH;
    const int bq  = pix / (WW * HH);
    float sc[16], sh[16];
#pragma unroll
    for (int c = 0; c < 16; ++c) {
        const float s = gamma[c] * rsqrtf(var[c] + 1e-3f);
        sc[c] = s;
        sh[c] = beta[c] - mean[c] * s;
    }
    float a0 = 0.f, a1 = 0.f;
#pragma unroll
    for (int dy = -1; dy <= 1; ++dy) {
        const int yy = hq + dy;
        if ((unsigned)yy >= HH) continue;
#pragma unroll
        for (int dx = -1; dx <= 1; ++dx) {
            const int xx = wq + dx;
            if ((unsigned)xx >= WW) continue;
            const __hip_bfloat16* px = &xin[(((size_t)bq * HH + yy) * WW + xx) * 16];
            const float* wp = &fw[((dy + 1) * 3 + (dx + 1)) * 32];
#pragma unroll
            for (int c = 0; c < 16; ++c) {
                const float v = __bfloat162float(px[c]) * sc[c] + sh[c];
                a0 += v * wp[c * 2 + 0];
                a1 += v * wp[c * 2 + 1];
            }
        }
    }
    const float SC = sqrtf((float)(HH * HH + WW * WW));
    out[(size_t)pix * 2 + 0] = SC * a0;
    out[(size_t)pix * 2 + 1] = SC * a1;
}

// ---------------------------------------------------------------------------
// Workspace (bf16 elements), peak 132.2 MB:
//   cv [N*96] | t1 [N*128] | weights [43456]
//   t2 aliases cv[0:N*64], t4 = cv[N*64:N*80], t3 aliases t1[0:N*32]
// ---------------------------------------------------------------------------
extern "C" void kernel_launch(void* const* d_in, const int* in_sizes, int n_in,
                              void* d_out, int out_size, void* d_ws, size_t ws_size,
                              hipStream_t stream)
{
    const float* prv   = (const float*)d_in[0];
    const float* nxt   = (const float*)d_in[1];
    const float* dw0   = (const float*)d_in[2];
    const float* pw0   = (const float*)d_in[3];
    const float* b0    = (const float*)d_in[4];
    const float* dw1   = (const float*)d_in[5];
    const float* pw1   = (const float*)d_in[6];
    const float* b1    = (const float*)d_in[7];
    const float* dw2   = (const float*)d_in[8];
    const float* pw2   = (const float*)d_in[9];
    const float* b2    = (const float*)d_in[10];
    const float* dw3   = (const float*)d_in[11];
    const float* pw3   = (const float*)d_in[12];
    const float* b3    = (const float*)d_in[13];
    const float* bn_g  = (const float*)d_in[14];
    const float* bn_b  = (const float*)d_in[15];
    const float* bn_m  = (const float*)d_in[16];
    const float* bn_v  = (const float*)d_in[17];
    const float* fw    = (const float*)d_in[18];
    float* outp = (float*)d_out;

    const size_t N = (size_t)NPIX;
    __hip_bfloat16* ws  = (__hip_bfloat16*)d_ws;
    __hip_bfloat16* cv  = ws;                    // [N][96]
    __hip_bfloat16* t1  = ws + N * 96;           // [N][128]
    __hip_bfloat16* t2  = ws;                    // [N][64]  alias cv
    __hip_bfloat16* t3  = t1;                    // [N][32]  alias t1
    __hip_bfloat16* t4  = ws + N * 64;           // [N][16]  tail of cv region
    __hip_bfloat16* wts = ws + N * 224;          // 43456 elements
    __hip_bfloat16* dwbf0 = wts;
    __hip_bfloat16* dwbf1 = wts + 2016;
    __hip_bfloat16* dwbf2 = wts + 3168;
    __hip_bfloat16* dwbf3 = wts + 3744;
    __hip_bfloat16* Bt0   = wts + 4032;
    __hip_bfloat16* Bt1   = wts + 32704;
    __hip_bfloat16* Bt2   = wts + 40896;
    __hip_bfloat16* Bt3   = wts + 42944;

    prep_kernel<<<170, 256, 0, stream>>>(dw0, pw0, dw1, pw1, dw2, pw2, dw3, pw3, wts);
    cost_mfma_kernel<<<3 * HH * BB, 256, 0, stream>>>(prv, nxt, cv);
    sepconv_mfma<224, 128, 1><<<2304, 256, 0, stream>>>(cv, prv, nxt, dwbf0, Bt0, b0, t1);
    sepconv_mfma<128,  64, 0><<<2304, 256, 0, stream>>>(t1, nullptr, nullptr, dwbf1, Bt1, b1, t2);
    sepconv_mfma< 64,  32, 0><<<2304, 256, 0, stream>>>(t2, nullptr, nullptr, dwbf2, Bt2, b2, t3);
    sepconv_mfma< 32,  16, 0><<<2304, 256, 0, stream>>>(t3, nullptr, nullptr, dwbf3, Bt3, b3, t4);
    bn_flow_kernel<<<NPIX / 256, 256, 0, stream>>>(t4, bn_g, bn_b, bn_m, bn_v, fw, outp);
}

// Round 5
// 549.634 us; speedup vs baseline: 3.8732x; 1.0290x over previous
//
#include <hip/hip_runtime.h>
#include <hip/hip_bf16.h>

// Problem constants
#define BB 8
#define HH 192
#define WW 192
#define CC0 64
#define NPIX (BB*HH*WW) // 294912
#define NCV 81
#define CVP 96          // cv padded channels in fallback layout

typedef __attribute__((ext_vector_type(8))) short short8;
typedef __attribute__((ext_vector_type(4))) short short4v;
typedef __attribute__((ext_vector_type(4))) float f32x4;

__device__ __forceinline__ float bf2f(short s) {
    union { unsigned u; float f; } x; x.u = ((unsigned)(unsigned short)s) << 16; return x.f;
}
__device__ __forceinline__ short f2bf(float f) {
    __hip_bfloat16 h = __float2bfloat16(f);
    return *reinterpret_cast<short*>(&h);
}
__device__ __forceinline__ void cvt8(const short8 iv, float* fv) {
    const int* ip = (const int*)&iv;
#pragma unroll
    for (int e = 0; e < 4; ++e) {
        union { unsigned u; float f; } lo, hi;
        lo.u = ((unsigned)ip[e]) << 16;
        hi.u = ((unsigned)ip[e]) & 0xffff0000u;
        fv[2 * e] = lo.f; fv[2 * e + 1] = hi.f;
    }
}

__device__ __forceinline__ float mish_f(float v) {
    if (v > 20.0f) return v;
    const float u = __expf(v);
    const float n = u * (u + 2.0f);
    return v * n / (n + 2.0f);
}

// ---------------------------------------------------------------------------
// Weight prep (bf16 Bt matrices, channel order [prv|nxt|cv|pad]) — as R4.
// ---------------------------------------------------------------------------
__global__ __launch_bounds__(256) void prep_kernel(
    const float* __restrict__ dw0, const float* __restrict__ pw0,
    const float* __restrict__ dw1, const float* __restrict__ pw1,
    const float* __restrict__ dw2, const float* __restrict__ pw2,
    const float* __restrict__ dw3, const float* __restrict__ pw3,
    __hip_bfloat16* __restrict__ wout)
{
    const int u = blockIdx.x * 256 + threadIdx.x;
    if (u >= 43456) return;
    float v = 0.f;
    if (u < 2016) {                     // legacy dwbf0 slot (unused, kept for layout)
        const int t = u / 224, c = u % 224;
        if (c < 64)       v = dw0[t*209 + 81  + c];
        else if (c < 128) v = dw0[t*209 + 145 + (c-64)];
        else if (c < 209) v = dw0[t*209 + (c-128)];
    } else if (u < 3168) {
        const int r = u-2016, t = r/128, c = r%128; v = dw1[t*128+c];
    } else if (u < 3744) {
        const int r = u-3168, t = r/64, c = r%64; v = dw2[t*64+c];
    } else if (u < 4032) {
        const int r = u-3744, t = r/32, c = r%32; v = dw3[t*32+c];
    } else if (u < 32704) {             // Bt0 [128][224]
        const int r = u-4032, n = r/224, c = r%224;
        if (c < 64)       v = pw0[(81+c)*128 + n];
        else if (c < 128) v = pw0[(145+(c-64))*128 + n];
        else if (c < 209) v = pw0[(c-128)*128 + n];
    } else if (u < 40896) {             // Bt1 [64][128]
        const int r = u-32704, n = r/128, c = r%128; v = pw1[c*64 + n];
    } else if (u < 42944) {             // Bt2 [32][64]
        const int r = u-40896, n = r/64, c = r%64; v = pw2[c*32 + n];
    } else {                            // Bt3 [16][32]
        const int r = u-42944, n = r/32, c = r%32; v = pw3[c*16 + n];
    }
    wout[u] = __float2bfloat16(v);
}

// ---------------------------------------------------------------------------
// prep2: f32 dw weights (stage0 permuted to [prv|nxt|cv|pad]) + fused BN*flow
// weights. fout: dwf0[2016] dwf1[1152] dwf2[576] dwf3[288] fwp[288] tb[18]
// ---------------------------------------------------------------------------
__global__ __launch_bounds__(256) void prep2_kernel(
    const float* __restrict__ dw0, const float* __restrict__ dw1,
    const float* __restrict__ dw2, const float* __restrict__ dw3,
    const float* __restrict__ bn_g, const float* __restrict__ bn_b,
    const float* __restrict__ bn_m, const float* __restrict__ bn_v,
    const float* __restrict__ fw, float* __restrict__ fout)
{
    const int u = blockIdx.x * 256 + threadIdx.x;
    if (u >= 4338) return;
    float v = 0.f;
    if (u < 2016) {
        const int t = u / 224, c = u % 224;
        if (c < 64)       v = dw0[t*209 + 81  + c];
        else if (c < 128) v = dw0[t*209 + 145 + (c-64)];
        else if (c < 209) v = dw0[t*209 + (c-128)];
    } else if (u < 3168) {
        const int r = u-2016, t = r/128, c = r%128; v = dw1[t*128+c];
    } else if (u < 3744) {
        const int r = u-3168, t = r/64, c = r%64; v = dw2[t*64+c];
    } else if (u < 4032) {
        const int r = u-3744, t = r/32, c = r%32; v = dw3[t*32+c];
    } else if (u < 4320) {              // fwp[t][c][s] = sc[c]*fw[t][c][s]
        const int r = u-4032, t = r/32, rem = r%32, c = rem >> 1, s = rem & 1;
        const float sc = bn_g[c] * rsqrtf(bn_v[c] + 1e-3f);
        v = sc * fw[t*32 + c*2 + s];
    } else {                            // tb[t][s] = sum_c sh[c]*fw[t][c][s]
        const int r = u-4320, t = r/2, s = r%2;
        float a = 0.f;
        for (int c = 0; c < 16; ++c) {
            const float sc = bn_g[c] * rsqrtf(bn_v[c] + 1e-3f);
            const float sh = bn_b[c] - bn_m[c] * sc;
            a += sh * fw[t*32 + c*2 + s];
        }
        v = a;
    }
    fout[u] = v;
}

// ---------------------------------------------------------------------------
// Cost volume via MFMA banded QK^T (R4 structure, passed).
// UNIFIED=1: also dump bf16 prv (via LDS transpose of A-frags) and bf16 nxt
// (from the r==4 staged row) into x0b[N][224] = [prv|nxt|cv96].
// ---------------------------------------------------------------------------
template<int UNIFIED>
__global__ __launch_bounds__(256) void cost_mfma_kernel(
    const float* __restrict__ prv, const float* __restrict__ nxt,
    __hip_bfloat16* __restrict__ xout)
{
    constexpr int OST   = UNIFIED ? 224 : CVP;
    constexpr int CVOFF = UNIFIED ? 128 : 0;

    __shared__ __align__(16) short sNxt[80][70];
    __shared__ __align__(16) short sCv[64][96];

    const int tid  = threadIdx.x;
    const int lane = tid & 63;
    const int wv   = tid >> 6;
    const int ln15 = lane & 15;
    const int kq   = lane >> 4;

    const int bx = blockIdx.x;
    const int tw = bx % 3;
    const int h  = (bx / 3) % HH;
    const int b  = bx / (3 * HH);
    const int w0 = tw * 64;

    {
        const short8 z = {0,0,0,0,0,0,0,0};
        for (int t = 0; t < 3; ++t) {
            const int idx = tid + t * 256;
            const int px = idx / 12, c8 = idx % 12;
            *(short8*)&sCv[px][c8 * 8] = z;
        }
    }

    short8 af0, af1;
    {
        const int apx = w0 + wv * 16 + ln15;
        const float* ap = prv + (((size_t)b * HH + h) * WW + apx) * CC0 + kq * 8;
        const float4 x0 = *(const float4*)(ap);
        const float4 x1 = *(const float4*)(ap + 4);
        const float4 x2 = *(const float4*)(ap + 32);
        const float4 x3 = *(const float4*)(ap + 36);
        af0[0]=f2bf(x0.x); af0[1]=f2bf(x0.y); af0[2]=f2bf(x0.z); af0[3]=f2bf(x0.w);
        af0[4]=f2bf(x1.x); af0[5]=f2bf(x1.y); af0[6]=f2bf(x1.z); af0[7]=f2bf(x1.w);
        af1[0]=f2bf(x2.x); af1[1]=f2bf(x2.y); af1[2]=f2bf(x2.z); af1[3]=f2bf(x2.w);
        af1[4]=f2bf(x3.x); af1[5]=f2bf(x3.y); af1[6]=f2bf(x3.z); af1[7]=f2bf(x3.w);
    }

    const int m0 = wv * 16;
    short* outp = (short*)xout + (((size_t)b * HH + h) * WW + w0) * OST;

    for (int r = 0; r < 9; ++r) {
        const int y = h - 4 + r;
        const bool yok = ((unsigned)y < (unsigned)HH);
        __syncthreads();
        if (yok) {
            const float* rowp = nxt + (((size_t)b * HH + y) * WW) * CC0;
#pragma unroll
            for (int t = 0; t < 5; ++t) {
                const int idx = tid + t * 256;
                const int px  = idx >> 4;
                const int c4  = idx & 15;
                const int gw  = w0 - 4 + px;
                float4 v = make_float4(0.f, 0.f, 0.f, 0.f);
                if ((unsigned)gw < (unsigned)WW)
                    v = *(const float4*)(rowp + (size_t)gw * CC0 + c4 * 4);
                short4v sv;
                sv[0]=f2bf(v.x); sv[1]=f2bf(v.y); sv[2]=f2bf(v.z); sv[3]=f2bf(v.w);
                *(short4v*)&sNxt[px][c4 * 4] = sv;
            }
        }
        __syncthreads();
        if (!yok) continue;

#pragma unroll
        for (int j = 0; j < 2; ++j) {
            const short* bp = &sNxt[m0 + j * 16 + ln15][kq * 8];
            const short8 b0 = *(const short8*)bp;
            const short8 b1 = *(const short8*)(bp + 32);
            f32x4 acc = {0.f, 0.f, 0.f, 0.f};
            acc = __builtin_amdgcn_mfma_f32_16x16x32_bf16(af0, b0, acc, 0, 0, 0);
            acc = __builtin_amdgcn_mfma_f32_16x16x32_bf16(af1, b1, acc, 0, 0, 0);
#pragma unroll
            for (int rr = 0; rr < 4; ++rr) {
                const int m  = kq * 4 + rr;
                const int dj = j * 16 + ln15 - m;
                if ((unsigned)dj < 9u) {
                    float mv = acc[rr] * (1.0f / 64.0f);
                    mv = (mv > 0.f) ? mv : 0.1f * mv;
                    sCv[m0 + m][r * 9 + dj] = f2bf(mv);
                }
            }
        }
        if (UNIFIED && r == 4) {
            // dump bf16 nxt for the 64 owned px (row y == h in sNxt[4..67])
#pragma unroll
            for (int t = 0; t < 2; ++t) {
                const int u = tid + t * 256;
                const int px = u >> 3, cg = u & 7;
                *(short8*)(outp + (size_t)px * OST + 64 + cg * 8) =
                    *(const short8*)&sNxt[4 + px][cg * 8];
            }
        }
    }

    __syncthreads();
    // cv store
#pragma unroll
    for (int t = 0; t < 3; ++t) {
        const int idx = tid + t * 256;
        const int px = idx / 12, c8 = idx % 12;
        *(short8*)(outp + (size_t)px * OST + CVOFF + c8 * 8) = *(const short8*)&sCv[px][c8 * 8];
    }
    if (UNIFIED) {
        // dump bf16 prv from A-frags via LDS transpose (sNxt reused as flat buf)
        short* sf = &sNxt[0][0];
        {
            const int px = wv * 16 + ln15;
            *(short8*)&sf[px * 64 + kq * 8] = af0;
            *(short8*)&sf[px * 64 + kq * 8 + 32] = af1;
        }
        __syncthreads();
#pragma unroll
        for (int t = 0; t < 2; ++t) {
            const int u = tid + t * 256;
            const int px = u >> 3, cg = u & 7;
            *(short8*)(outp + (size_t)px * OST + cg * 8) = *(const short8*)&sf[px * 64 + cg * 8];
        }
    }
}

// ---------------------------------------------------------------------------
// Fused sepconv: dw3x3 (f32 weights from SGPRs) -> bf16 MFMA -> bias+mish.
// MODE 0: bf16 input, stride KP. MODE 1: fallback 3-source [cv96|prv f32|nxt f32].
// ---------------------------------------------------------------------------
template<int KP, int COUT, int MODE>
__global__ __launch_bounds__(256) void sepconv_mfma(
    const __hip_bfloat16* __restrict__ in,
    const float* __restrict__ prv, const float* __restrict__ nxt,
    const float* __restrict__ dwf,             // [9][KP] f32
    const __hip_bfloat16* __restrict__ Bt,     // [COUT][KP]
    const float* __restrict__ bias,
    __hip_bfloat16* __restrict__ out)
{
    constexpr int NT  = COUT / 16;
    constexpr int WGN = (NT >= 2) ? 2 : 1;
    constexpr int WGM = 4 / WGN;
    constexpr int TM  = 8 / WGM;
    constexpr int TN  = NT / WGN;

    __shared__ __align__(16) short sIn[6][34][32];
    __shared__ __align__(16) short sA[4][128][8];
    __shared__ __align__(16) short sB[4][COUT][8];

    const int tid  = threadIdx.x;
    const int lane = tid & 63;
    const int wv   = tid >> 6;
    const int ln15 = lane & 15;
    const int kq   = lane >> 4;
    const int wm   = wv % WGM;
    const int wn   = wv / WGM;

    const int bx = blockIdx.x;
    const int tw = bx % 6;
    const int th = (bx / 6) % 48;
    const int bb = bx / 288;
    const int w0 = tw * 32, h0 = th * 4;

    // depthwise: wave-uniform k-slice (SGPR weights), lane = px column/pair
    const int dkbu = __builtin_amdgcn_readfirstlane(wv);
    const int dww  = lane & 31;
    const int dhh  = (lane >> 5) * 2;

    f32x4 acc[TM][TN] = {};

    for (int k0 = 0; k0 < KP; k0 += 32) {
        // --- stage input halo tile (34x6 px, 32 ch) ---
        for (int u = tid; u < 816; u += 256) {
            const int kb = u & 3;
            const int p  = u >> 2;
            const int iw = p % 34, ih = p / 34;
            const int gw = w0 - 1 + iw, gh = h0 - 1 + ih;
            short8 v = {0,0,0,0,0,0,0,0};
            if ((unsigned)gw < (unsigned)WW && (unsigned)gh < (unsigned)HH) {
                const size_t pix = ((size_t)bb * HH + gh) * WW + gw;
                const int c0 = k0 + kb * 8;
                if (MODE == 0) {
                    v = *(const short8*)((const short*)in + pix * KP + c0);
                } else {
                    if (c0 < 64) {
                        const float4* s = (const float4*)(prv + pix * 64 + c0);
                        const float4 a = s[0], bq = s[1];
                        v[0]=f2bf(a.x);  v[1]=f2bf(a.y);  v[2]=f2bf(a.z);  v[3]=f2bf(a.w);
                        v[4]=f2bf(bq.x); v[5]=f2bf(bq.y); v[6]=f2bf(bq.z); v[7]=f2bf(bq.w);
                    } else if (c0 < 128) {
                        const float4* s = (const float4*)(nxt + pix * 64 + (c0 - 64));
                        const float4 a = s[0], bq = s[1];
                        v[0]=f2bf(a.x);  v[1]=f2bf(a.y);  v[2]=f2bf(a.z);  v[3]=f2bf(a.w);
                        v[4]=f2bf(bq.x); v[5]=f2bf(bq.y); v[6]=f2bf(bq.z); v[7]=f2bf(bq.w);
                    } else {
                        v = *(const short8*)((const short*)in + pix * CVP + (c0 - 128));
                    }
                }
            }
            *(short8*)&sIn[ih][iw][kb * 8] = v;
        }
        // --- stage Bt chunk ---
        for (int u = tid; u < COUT * 4; u += 256) {
            const int n = u >> 2, kb = u & 3;
            short8 v = *(const short8*)((const short*)Bt + (size_t)n * KP + k0 + kb * 8);
            *(short8*)&sB[kb][n ^ (kb << 2)][0] = v;
        }
        __syncthreads();

        // --- depthwise: 2 vertically-adjacent px, 8 ch; f32 SGPR weights ---
        {
            const float* wrow = dwf + k0 + dkbu * 8;
            float r0[8] = {0,0,0,0,0,0,0,0};
            float r1[8] = {0,0,0,0,0,0,0,0};
#pragma unroll
            for (int dy = 0; dy < 4; ++dy) {
#pragma unroll
                for (int dx = 0; dx < 3; ++dx) {
                    const short8 iv = *(const short8*)&sIn[dhh + dy][dww + dx][dkbu * 8];
                    float fv[8];
                    cvt8(iv, fv);
                    if (dy < 3) {
#pragma unroll
                        for (int j = 0; j < 8; ++j)
                            r0[j] += fv[j] * wrow[(dy * 3 + dx) * KP + j];
                    }
                    if (dy >= 1) {
#pragma unroll
                        for (int j = 0; j < 8; ++j)
                            r1[j] += fv[j] * wrow[((dy - 1) * 3 + dx) * KP + j];
                    }
                }
            }
            const int px0 = dhh * 32 + dww;
            short8 o0, o1;
#pragma unroll
            for (int j = 0; j < 8; ++j) { o0[j] = f2bf(r0[j]); o1[j] = f2bf(r1[j]); }
            *(short8*)&sA[dkbu][px0 ^ (dkbu << 2)][0] = o0;
            *(short8*)&sA[dkbu][(px0 + 32) ^ (dkbu << 2)][0] = o1;
        }
        __syncthreads();

        // --- MFMA ---
        short8 af[TM], bf8[TN];
#pragma unroll
        for (int i = 0; i < TM; ++i) {
            const int m = (wm * TM + i) * 16 + ln15;
            af[i] = *(const short8*)&sA[kq][m ^ (kq << 2)][0];
        }
#pragma unroll
        for (int j = 0; j < TN; ++j) {
            const int n = (wn * TN + j) * 16 + ln15;
            bf8[j] = *(const short8*)&sB[kq][n ^ (kq << 2)][0];
        }
#pragma unroll
        for (int i = 0; i < TM; ++i)
#pragma unroll
            for (int j = 0; j < TN; ++j)
                acc[i][j] = __builtin_amdgcn_mfma_f32_16x16x32_bf16(
                    af[i], bf8[j], acc[i][j], 0, 0, 0);
        __syncthreads();
    }

#pragma unroll
    for (int j = 0; j < TN; ++j) {
        const int n = (wn * TN + j) * 16 + ln15;
        const float bj = bias[n];
#pragma unroll
        for (int i = 0; i < TM; ++i) {
#pragma unroll
            for (int r = 0; r < 4; ++r) {
                const int m  = (wm * TM + i) * 16 + kq * 4 + r;
                const int gh = h0 + (m >> 5), gw = w0 + (m & 31);
                const size_t gp = ((size_t)bb * HH + gh) * WW + gw;
                out[gp * COUT + n] = __float2bfloat16(mish_f(acc[i][j][r] + bj));
            }
        }
    }
}

// ---------------------------------------------------------------------------
// BN folded into flow conv: out = SC * sum_{taps in-bounds} (tb[t] + x.fwp[t])
// fwp/tb uniform -> scalar (SGPR) loads.
// ---------------------------------------------------------------------------
__global__ __launch_bounds__(256) void bn_flow_kernel(
    const __hip_bfloat16* __restrict__ xin,
    const float* __restrict__ fwp, const float* __restrict__ tbv,
    float* __restrict__ out)
{
    const int pix = blockIdx.x * 256 + threadIdx.x;
    const int wq  = pix % WW;
    const int hq  = (pix / WW) % HH;
    const int bq  = pix / (WW * HH);
    float a0 = 0.f, a1 = 0.f;
#pragma unroll
    for (int dy = -1; dy <= 1; ++dy) {
        const int yy = hq + dy;
        if ((unsigned)yy >= HH) continue;
#pragma unroll
        for (int dx = -1; dx <= 1; ++dx) {
            const int xx = wq + dx;
            if ((unsigned)xx >= WW) continue;
            const int t = (dy + 1) * 3 + (dx + 1);
            a0 += tbv[t * 2 + 0];
            a1 += tbv[t * 2 + 1];
            const short* xp = (const short*)xin + (((size_t)bq * HH + yy) * WW + xx) * 16;
            const short8 v0 = *(const short8*)xp;
            const short8 v1 = *(const short8*)(xp + 8);
            float x[16];
            cvt8(v0, x); cvt8(v1, x + 8);
            const float* wp = fwp + t * 32;
#pragma unroll
            for (int c = 0; c < 16; ++c) {
                a0 += x[c] * wp[c * 2 + 0];
                a1 += x[c] * wp[c * 2 + 1];
            }
        }
    }
    const float SC = sqrtf((float)(HH * HH + WW * WW));
    out[(size_t)pix * 2 + 0] = SC * a0;
    out[(size_t)pix * 2 + 1] = SC * a1;
}

// ---------------------------------------------------------------------------
// Workspace:
// UNIFIED (ws >= ~208 MB): x0b[N][224] | t1[N][128] | wts bf16 | f32 wts
// FALLBACK (ws >= ~133 MB): cv[N][96]  | t1[N][128] | wts bf16 | f32 wts
// t2 = ws[0:N*64], t3 = t1, t4 = ws[N*64:N*80] in both.
// ---------------------------------------------------------------------------
extern "C" void kernel_launch(void* const* d_in, const int* in_sizes, int n_in,
                              void* d_out, int out_size, void* d_ws, size_t ws_size,
                              hipStream_t stream)
{
    const float* prv   = (const float*)d_in[0];
    const float* nxt   = (const float*)d_in[1];
    const float* dw0   = (const float*)d_in[2];
    const float* pw0   = (const float*)d_in[3];
    const float* b0    = (const float*)d_in[4];
    const float* dw1   = (const float*)d_in[5];
    const float* pw1   = (const float*)d_in[6];
    const float* b1    = (const float*)d_in[7];
    const float* dw2   = (const float*)d_in[8];
    const float* pw2   = (const float*)d_in[9];
    const float* b2    = (const float*)d_in[10];
    const float* dw3   = (const float*)d_in[11];
    const float* pw3   = (const float*)d_in[12];
    const float* b3    = (const float*)d_in[13];
    const float* bn_g  = (const float*)d_in[14];
    const float* bn_b  = (const float*)d_in[15];
    const float* bn_m  = (const float*)d_in[16];
    const float* bn_v  = (const float*)d_in[17];
    const float* fw    = (const float*)d_in[18];
    float* outp = (float*)d_out;

    const size_t N = (size_t)NPIX;
    __hip_bfloat16* ws = (__hip_bfloat16*)d_ws;

    const size_t need_uni = (N * 352 + 43456) * 2 + 4338 * 4;
    const bool uni = (ws_size >= need_uni);

    __hip_bfloat16* t1  = uni ? (ws + N * 224) : (ws + N * 96);
    __hip_bfloat16* wts = uni ? (ws + N * 352) : (ws + N * 224);
    __hip_bfloat16* t2  = ws;                    // aliases x0b/cv (dead then)
    __hip_bfloat16* t3  = t1;
    __hip_bfloat16* t4  = ws + N * 64;
    __hip_bfloat16* Bt0 = wts + 4032;
    __hip_bfloat16* Bt1 = wts + 32704;
    __hip_bfloat16* Bt2 = wts + 40896;
    __hip_bfloat16* Bt3 = wts + 42944;
    float* fwt = (float*)(wts + 43456);          // dwf0|dwf1|dwf2|dwf3|fwp|tb

    prep_kernel<<<170, 256, 0, stream>>>(dw0, pw0, dw1, pw1, dw2, pw2, dw3, pw3, wts);
    prep2_kernel<<<17, 256, 0, stream>>>(dw0, dw1, dw2, dw3,
                                         bn_g, bn_b, bn_m, bn_v, fw, fwt);
    if (uni) {
        cost_mfma_kernel<1><<<3 * HH * BB, 256, 0, stream>>>(prv, nxt, ws);
        sepconv_mfma<224, 128, 0><<<2304, 256, 0, stream>>>(ws, nullptr, nullptr,
                                                            fwt, Bt0, b0, t1);
    } else {
        cost_mfma_kernel<0><<<3 * HH * BB, 256, 0, stream>>>(prv, nxt, ws);
        sepconv_mfma<224, 128, 1><<<2304, 256, 0, stream>>>(ws, prv, nxt,
                                                            fwt, Bt0, b0, t1);
    }
    sepconv_mfma<128, 64, 0><<<2304, 256, 0, stream>>>(t1, nullptr, nullptr,
                                                       fwt + 2016, Bt1, b1, t2);
    sepconv_mfma<64, 32, 0><<<2304, 256, 0, stream>>>(t2, nullptr, nullptr,
                                                      fwt + 3168, Bt2, b2, t3);
    sepconv_mfma<32, 16, 0><<<2304, 256, 0, stream>>>(t3, nullptr, nullptr,
                                                      fwt + 3744, Bt3, b3, t4);
    bn_flow_kernel<<<NPIX / 256, 256, 0, stream>>>(t4, fwt + 4032, fwt + 4320, outp);
}

// Round 6
// 537.502 us; speedup vs baseline: 3.9607x; 1.0226x over previous
//
#include <hip/hip_runtime.h>
#include <hip/hip_bf16.h>

// Problem constants
#define BB 8
#define HH 192
#define WW 192
#define CC0 64
#define NPIX (BB*HH*WW) // 294912
#define NCV 81
#define CVP 96          // cv padded channels in fallback layout

typedef __attribute__((ext_vector_type(8))) short short8;
typedef __attribute__((ext_vector_type(4))) short short4v;
typedef __attribute__((ext_vector_type(4))) float f32x4;

__device__ __forceinline__ float bf2f(short s) {
    union { unsigned u; float f; } x; x.u = ((unsigned)(unsigned short)s) << 16; return x.f;
}
__device__ __forceinline__ short f2bf(float f) {
    __hip_bfloat16 h = __float2bfloat16(f);
    return *reinterpret_cast<short*>(&h);
}
__device__ __forceinline__ void cvt8(const short8 iv, float* fv) {
    const int* ip = (const int*)&iv;
#pragma unroll
    for (int e = 0; e < 4; ++e) {
        union { unsigned u; float f; } lo, hi;
        lo.u = ((unsigned)ip[e]) << 16;
        hi.u = ((unsigned)ip[e]) & 0xffff0000u;
        fv[2 * e] = lo.f; fv[2 * e + 1] = hi.f;
    }
}

__device__ __forceinline__ float mish_f(float v) {
    if (v > 20.0f) return v;
    const float u = __expf(v);
    const float n = u * (u + 2.0f);
    return v * n / (n + 2.0f);
}

// ---------------------------------------------------------------------------
// Weight prep (bf16 Bt matrices, channel order [prv|nxt|cv|pad]) — as R4.
// ---------------------------------------------------------------------------
__global__ __launch_bounds__(256) void prep_kernel(
    const float* __restrict__ dw0, const float* __restrict__ pw0,
    const float* __restrict__ dw1, const float* __restrict__ pw1,
    const float* __restrict__ dw2, const float* __restrict__ pw2,
    const float* __restrict__ dw3, const float* __restrict__ pw3,
    __hip_bfloat16* __restrict__ wout)
{
    const int u = blockIdx.x * 256 + threadIdx.x;
    if (u >= 43456) return;
    float v = 0.f;
    if (u < 2016) {                     // legacy dwbf0 slot (unused, kept for layout)
        const int t = u / 224, c = u % 224;
        if (c < 64)       v = dw0[t*209 + 81  + c];
        else if (c < 128) v = dw0[t*209 + 145 + (c-64)];
        else if (c < 209) v = dw0[t*209 + (c-128)];
    } else if (u < 3168) {
        const int r = u-2016, t = r/128, c = r%128; v = dw1[t*128+c];
    } else if (u < 3744) {
        const int r = u-3168, t = r/64, c = r%64; v = dw2[t*64+c];
    } else if (u < 4032) {
        const int r = u-3744, t = r/32, c = r%32; v = dw3[t*32+c];
    } else if (u < 32704) {             // Bt0 [128][224]
        const int r = u-4032, n = r/224, c = r%224;
        if (c < 64)       v = pw0[(81+c)*128 + n];
        else if (c < 128) v = pw0[(145+(c-64))*128 + n];
        else if (c < 209) v = pw0[(c-128)*128 + n];
    } else if (u < 40896) {             // Bt1 [64][128]
        const int r = u-32704, n = r/128, c = r%128; v = pw1[c*64 + n];
    } else if (u < 42944) {             // Bt2 [32][64]
        const int r = u-40896, n = r/64, c = r%64; v = pw2[c*32 + n];
    } else {                            // Bt3 [16][32]
        const int r = u-42944, n = r/32, c = r%32; v = pw3[c*16 + n];
    }
    wout[u] = __float2bfloat16(v);
}

// ---------------------------------------------------------------------------
// prep2: f32 dw weights (stage0 permuted to [prv|nxt|cv|pad]) + fused BN*flow
// weights. fout: dwf0[2016] dwf1[1152] dwf2[576] dwf3[288] fwp[288] tb[18]
// ---------------------------------------------------------------------------
__global__ __launch_bounds__(256) void prep2_kernel(
    const float* __restrict__ dw0, const float* __restrict__ dw1,
    const float* __restrict__ dw2, const float* __restrict__ dw3,
    const float* __restrict__ bn_g, const float* __restrict__ bn_b,
    const float* __restrict__ bn_m, const float* __restrict__ bn_v,
    const float* __restrict__ fw, float* __restrict__ fout)
{
    const int u = blockIdx.x * 256 + threadIdx.x;
    if (u >= 4338) return;
    float v = 0.f;
    if (u < 2016) {
        const int t = u / 224, c = u % 224;
        if (c < 64)       v = dw0[t*209 + 81  + c];
        else if (c < 128) v = dw0[t*209 + 145 + (c-64)];
        else if (c < 209) v = dw0[t*209 + (c-128)];
    } else if (u < 3168) {
        const int r = u-2016, t = r/128, c = r%128; v = dw1[t*128+c];
    } else if (u < 3744) {
        const int r = u-3168, t = r/64, c = r%64; v = dw2[t*64+c];
    } else if (u < 4032) {
        const int r = u-3744, t = r/32, c = r%32; v = dw3[t*32+c];
    } else if (u < 4320) {              // fwp[t][c][s] = sc[c]*fw[t][c][s]
        const int r = u-4032, t = r/32, rem = r%32, c = rem >> 1, s = rem & 1;
        const float sc = bn_g[c] * rsqrtf(bn_v[c] + 1e-3f);
        v = sc * fw[t*32 + c*2 + s];
    } else {                            // tb[t][s] = sum_c sh[c]*fw[t][c][s]
        const int r = u-4320, t = r/2, s = r%2;
        float a = 0.f;
        for (int c = 0; c < 16; ++c) {
            const float sc = bn_g[c] * rsqrtf(bn_v[c] + 1e-3f);
            const float sh = bn_b[c] - bn_m[c] * sc;
            a += sh * fw[t*32 + c*2 + s];
        }
        v = a;
    }
    fout[u] = v;
}

// ---------------------------------------------------------------------------
// Cost volume v2: MFMA banded QK^T on a 32w x 4h output tile.
// 12 staged nxt rows serve 4 output rows (3x less re-read than 9-per-1).
// Double-buffered sNxt with register prefetch; 1 barrier per y.
// Wave wv: mt = wv&1 (16-px m-strip), jt = wv>>1 (16-wide n half of band).
// sNxt row idx = staged px (gw = w0-4+idx); dj = nb - m in [0,9) scatter.
// sNxt padded to 48 rows: jt=1/mt=1 frag reads idx up to 47 (discarded lanes).
// UNIFIED=1: also dump bf16 nxt (from staged LDS) and prv (L2-hot re-read)
// into x0b[N][224] = [prv|nxt|cv96].
// ---------------------------------------------------------------------------
template<int UNIFIED>
__global__ __launch_bounds__(256) void cost_mfma_kernel(
    const float* __restrict__ prv, const float* __restrict__ nxt,
    __hip_bfloat16* __restrict__ xout)
{
    constexpr int OST   = UNIFIED ? 224 : CVP;
    constexpr int CVOFF = UNIFIED ? 128 : 0;

    __shared__ __align__(16) short sNxt[2][48][70];
    __shared__ __align__(16) short sCv[4][32][96];

    const int tid  = threadIdx.x;
    const int lane = tid & 63;
    const int wv   = tid >> 6;
    const int ln15 = lane & 15;
    const int kq   = lane >> 4;
    const int mt   = wv & 1;
    const int jt   = wv >> 1;

    const int bx = blockIdx.x;
    const int tw = bx % 6;
    const int th = (bx / 6) % 48;
    const int b  = bx / 288;
    const int w0 = tw * 32, h0 = th * 4;

    // zero-init sCv: 4*32*12 = 1536 short8
    {
        const short8 z = {0,0,0,0,0,0,0,0};
#pragma unroll
        for (int t = 0; t < 6; ++t) {
            const int idx = tid + t * 256;
            const int row = idx / 384, rem = idx % 384;
            const int px = rem / 12, c8 = rem % 12;
            *(short8*)&sCv[row][px][c8 * 8] = z;
        }
    }

    // A fragments: prv[h0+r4][w0 + mt*16 + ln15][ch], khalf0: kq*8, khalf1: +32
    short8 af0[4], af1[4];
    {
        const int apx = w0 + mt * 16 + ln15;
#pragma unroll
        for (int r4 = 0; r4 < 4; ++r4) {
            const float* ap = prv + (((size_t)b * HH + h0 + r4) * WW + apx) * CC0 + kq * 8;
            const float4 x0 = *(const float4*)(ap);
            const float4 x1 = *(const float4*)(ap + 4);
            const float4 x2 = *(const float4*)(ap + 32);
            const float4 x3 = *(const float4*)(ap + 36);
            af0[r4][0]=f2bf(x0.x); af0[r4][1]=f2bf(x0.y); af0[r4][2]=f2bf(x0.z); af0[r4][3]=f2bf(x0.w);
            af0[r4][4]=f2bf(x1.x); af0[r4][5]=f2bf(x1.y); af0[r4][6]=f2bf(x1.z); af0[r4][7]=f2bf(x1.w);
            af1[r4][0]=f2bf(x2.x); af1[r4][1]=f2bf(x2.y); af1[r4][2]=f2bf(x2.z); af1[r4][3]=f2bf(x2.w);
            af1[r4][4]=f2bf(x3.x); af1[r4][5]=f2bf(x3.y); af1[r4][6]=f2bf(x3.z); af1[r4][7]=f2bf(x3.w);
        }
    }

    // staging helper indices: 40 px * 16 c4 = 640 float4s, 3 strided slots
    const int s_px = (tid & 0xFF) >> 4;   // placeholder; real idx per slot below

    // prologue: stage y0 = h0-4 into buf 0
    int cur = 0;
    {
        const int y0 = h0 - 4;
        if ((unsigned)y0 < (unsigned)HH) {
            const float* rowp = nxt + (((size_t)b * HH + y0) * WW) * CC0;
#pragma unroll
            for (int t = 0; t < 3; ++t) {
                const int u = tid + t * 256;
                if (u < 640) {
                    const int px = u >> 4, c4 = u & 15;
                    const int gw = w0 - 4 + px;
                    float4 v = make_float4(0.f, 0.f, 0.f, 0.f);
                    if ((unsigned)gw < (unsigned)WW)
                        v = *(const float4*)(rowp + (size_t)gw * CC0 + c4 * 4);
                    short4v sv;
                    sv[0]=f2bf(v.x); sv[1]=f2bf(v.y); sv[2]=f2bf(v.z); sv[3]=f2bf(v.w);
                    *(short4v*)&sNxt[0][px][c4 * 4] = sv;
                }
            }
        }
    }

    const size_t obase_blk = (((size_t)b * HH + h0) * WW + w0); // pix of (h0, w0)

    for (int i = 0; i < 12; ++i) {
        const int y = h0 - 4 + i;
        const bool yok = ((unsigned)y < (unsigned)HH);
        __syncthreads();   // sNxt[cur] ready; prev iter's reads done

        // --- prefetch y+1 into regs (loads issue now, consumed after compute) ---
        const int yn = y + 1;
        const bool nok = (i < 11) && ((unsigned)yn < (unsigned)HH);
        float4 sreg[3];
        if (nok) {
            const float* rowp = nxt + (((size_t)b * HH + yn) * WW) * CC0;
#pragma unroll
            for (int t = 0; t < 3; ++t) {
                const int u = tid + t * 256;
                sreg[t] = make_float4(0.f, 0.f, 0.f, 0.f);
                if (u < 640) {
                    const int px = u >> 4, c4 = u & 15;
                    const int gw = w0 - 4 + px;
                    if ((unsigned)gw < (unsigned)WW)
                        sreg[t] = *(const float4*)(rowp + (size_t)gw * CC0 + c4 * 4);
                }
            }
        }

        // --- compute y from sNxt[cur] ---
        if (yok) {
            const int nb = mt * 16 + jt * 16 + ln15;   // staged px idx (may be >=40, padded)
            const short* bp = &sNxt[cur][nb][kq * 8];
            const short8 b0 = *(const short8*)bp;
            const short8 b1 = *(const short8*)(bp + 32);
#pragma unroll
            for (int r4 = 0; r4 < 4; ++r4) {
                const int h = h0 + r4;
                const int rband = y - h + 4;
                if ((unsigned)rband <= 8u) {
                    f32x4 acc = {0.f, 0.f, 0.f, 0.f};
                    acc = __builtin_amdgcn_mfma_f32_16x16x32_bf16(af0[r4], b0, acc, 0, 0, 0);
                    acc = __builtin_amdgcn_mfma_f32_16x16x32_bf16(af1[r4], b1, acc, 0, 0, 0);
#pragma unroll
                    for (int rr = 0; rr < 4; ++rr) {
                        const int m_local = kq * 4 + rr;
                        const int dj = jt * 16 + ln15 - m_local;
                        if ((unsigned)dj < 9u) {
                            float mv = acc[rr] * (1.0f / 64.0f);
                            mv = (mv > 0.f) ? mv : 0.1f * mv;
                            sCv[r4][mt * 16 + m_local][rband * 9 + dj] = f2bf(mv);
                        }
                    }
                }
            }
            // dump bf16 nxt for owned rows (staged idx 4..35 = gw w0..w0+31)
            if (UNIFIED && y >= h0 && y < h0 + 4) {
                const int px_o = tid >> 3, cg = tid & 7;   // 32 px x 8 groups = 256
                short* op = (short*)xout + (((size_t)b * HH + y) * WW + w0 + px_o) * OST
                            + 64 + cg * 8;
                *(short8*)op = *(const short8*)&sNxt[cur][4 + px_o][cg * 8];
            }
        }

        // --- convert + write prefetched row to sNxt[cur^1] ---
        if (nok) {
#pragma unroll
            for (int t = 0; t < 3; ++t) {
                const int u = tid + t * 256;
                if (u < 640) {
                    const int px = u >> 4, c4 = u & 15;
                    short4v sv;
                    sv[0]=f2bf(sreg[t].x); sv[1]=f2bf(sreg[t].y);
                    sv[2]=f2bf(sreg[t].z); sv[3]=f2bf(sreg[t].w);
                    *(short4v*)&sNxt[cur ^ 1][px][c4 * 4] = sv;
                }
            }
        }
        cur ^= 1;
    }

    __syncthreads();
    // cv flush: 4 rows x 32 px x 12 c8
#pragma unroll
    for (int t = 0; t < 6; ++t) {
        const int idx = tid + t * 256;
        const int row = idx / 384, rem = idx % 384;
        const int px = rem / 12, c8 = rem % 12;
        short* op = (short*)xout + (obase_blk + (size_t)row * WW + px) * OST + CVOFF + c8 * 8;
        *(short8*)op = *(const short8*)&sCv[row][px][c8 * 8];
    }
    if (UNIFIED) {
        // prv dump: 4 rows x 32 px x 8 cg, re-read f32 (L2-hot), coalesced
#pragma unroll
        for (int t = 0; t < 4; ++t) {
            const int u = tid + t * 256;
            const int row = u >> 8, px = (u >> 3) & 31, cg = u & 7;
            const float* ap = prv + (obase_blk + (size_t)row * WW + px) * CC0 + cg * 8;
            const float4 x0 = *(const float4*)(ap);
            const float4 x1 = *(const float4*)(ap + 4);
            short8 v;
            v[0]=f2bf(x0.x); v[1]=f2bf(x0.y); v[2]=f2bf(x0.z); v[3]=f2bf(x0.w);
            v[4]=f2bf(x1.x); v[5]=f2bf(x1.y); v[6]=f2bf(x1.z); v[7]=f2bf(x1.w);
            short* op = (short*)xout + (obase_blk + (size_t)row * WW + px) * OST + cg * 8;
            *(short8*)op = v;
        }
    }
}

// ---------------------------------------------------------------------------
// Fused sepconv: dw3x3 (f32 weights from SGPRs) -> bf16 MFMA -> bias+mish.
// MODE 0: bf16 input, stride KP. MODE 1: fallback 3-source [cv96|prv f32|nxt f32].
// ---------------------------------------------------------------------------
template<int KP, int COUT, int MODE>
__global__ __launch_bounds__(256) void sepconv_mfma(
    const __hip_bfloat16* __restrict__ in,
    const float* __restrict__ prv, const float* __restrict__ nxt,
    const float* __restrict__ dwf,             // [9][KP] f32
    const __hip_bfloat16* __restrict__ Bt,     // [COUT][KP]
    const float* __restrict__ bias,
    __hip_bfloat16* __restrict__ out)
{
    constexpr int NT  = COUT / 16;
    constexpr int WGN = (NT >= 2) ? 2 : 1;
    constexpr int WGM = 4 / WGN;
    constexpr int TM  = 8 / WGM;
    constexpr int TN  = NT / WGN;

    __shared__ __align__(16) short sIn[6][34][32];
    __shared__ __align__(16) short sA[4][128][8];
    __shared__ __align__(16) short sB[4][COUT][8];

    const int tid  = threadIdx.x;
    const int lane = tid & 63;
    const int wv   = tid >> 6;
    const int ln15 = lane & 15;
    const int kq   = lane >> 4;
    const int wm   = wv % WGM;
    const int wn   = wv / WGM;

    const int bx = blockIdx.x;
    const int tw = bx % 6;
    const int th = (bx / 6) % 48;
    const int bb = bx / 288;
    const int w0 = tw * 32, h0 = th * 4;

    // depthwise: wave-uniform k-slice (SGPR weights), lane = px column/pair
    const int dkbu = __builtin_amdgcn_readfirstlane(wv);
    const int dww  = lane & 31;
    const int dhh  = (lane >> 5) * 2;

    f32x4 acc[TM][TN] = {};

    for (int k0 = 0; k0 < KP; k0 += 32) {
        // --- stage input halo tile (34x6 px, 32 ch) ---
        for (int u = tid; u < 816; u += 256) {
            const int kb = u & 3;
            const int p  = u >> 2;
            const int iw = p % 34, ih = p / 34;
            const int gw = w0 - 1 + iw, gh = h0 - 1 + ih;
            short8 v = {0,0,0,0,0,0,0,0};
            if ((unsigned)gw < (unsigned)WW && (unsigned)gh < (unsigned)HH) {
                const size_t pix = ((size_t)bb * HH + gh) * WW + gw;
                const int c0 = k0 + kb * 8;
                if (MODE == 0) {
                    v = *(const short8*)((const short*)in + pix * KP + c0);
                } else {
                    if (c0 < 64) {
                        const float4* s = (const float4*)(prv + pix * 64 + c0);
                        const float4 a = s[0], bq = s[1];
                        v[0]=f2bf(a.x);  v[1]=f2bf(a.y);  v[2]=f2bf(a.z);  v[3]=f2bf(a.w);
                        v[4]=f2bf(bq.x); v[5]=f2bf(bq.y); v[6]=f2bf(bq.z); v[7]=f2bf(bq.w);
                    } else if (c0 < 128) {
                        const float4* s = (const float4*)(nxt + pix * 64 + (c0 - 64));
                        const float4 a = s[0], bq = s[1];
                        v[0]=f2bf(a.x);  v[1]=f2bf(a.y);  v[2]=f2bf(a.z);  v[3]=f2bf(a.w);
                        v[4]=f2bf(bq.x); v[5]=f2bf(bq.y); v[6]=f2bf(bq.z); v[7]=f2bf(bq.w);
                    } else {
                        v = *(const short8*)((const short*)in + pix * CVP + (c0 - 128));
                    }
                }
            }
            *(short8*)&sIn[ih][iw][kb * 8] = v;
        }
        // --- stage Bt chunk ---
        for (int u = tid; u < COUT * 4; u += 256) {
            const int n = u >> 2, kb = u & 3;
            short8 v = *(const short8*)((const short*)Bt + (size_t)n * KP + k0 + kb * 8);
            *(short8*)&sB[kb][n ^ (kb << 2)][0] = v;
        }
        __syncthreads();

        // --- depthwise: 2 vertically-adjacent px, 8 ch; f32 SGPR weights ---
        {
            const float* wrow = dwf + k0 + dkbu * 8;
            float r0[8] = {0,0,0,0,0,0,0,0};
            float r1[8] = {0,0,0,0,0,0,0,0};
#pragma unroll
            for (int dy = 0; dy < 4; ++dy) {
#pragma unroll
                for (int dx = 0; dx < 3; ++dx) {
                    const short8 iv = *(const short8*)&sIn[dhh + dy][dww + dx][dkbu * 8];
                    float fv[8];
                    cvt8(iv, fv);
                    if (dy < 3) {
#pragma unroll
                        for (int j = 0; j < 8; ++j)
                            r0[j] += fv[j] * wrow[(dy * 3 + dx) * KP + j];
                    }
                    if (dy >= 1) {
#pragma unroll
                        for (int j = 0; j < 8; ++j)
                            r1[j] += fv[j] * wrow[((dy - 1) * 3 + dx) * KP + j];
                    }
                }
            }
            const int px0 = dhh * 32 + dww;
            short8 o0, o1;
#pragma unroll
            for (int j = 0; j < 8; ++j) { o0[j] = f2bf(r0[j]); o1[j] = f2bf(r1[j]); }
            *(short8*)&sA[dkbu][px0 ^ (dkbu << 2)][0] = o0;
            *(short8*)&sA[dkbu][(px0 + 32) ^ (dkbu << 2)][0] = o1;
        }
        __syncthreads();

        // --- MFMA ---
        short8 af[TM], bf8[TN];
#pragma unroll
        for (int i = 0; i < TM; ++i) {
            const int m = (wm * TM + i) * 16 + ln15;
            af[i] = *(const short8*)&sA[kq][m ^ (kq << 2)][0];
        }
#pragma unroll
        for (int j = 0; j < TN; ++j) {
            const int n = (wn * TN + j) * 16 + ln15;
            bf8[j] = *(const short8*)&sB[kq][n ^ (kq << 2)][0];
        }
#pragma unroll
        for (int i = 0; i < TM; ++i)
#pragma unroll
            for (int j = 0; j < TN; ++j)
                acc[i][j] = __builtin_amdgcn_mfma_f32_16x16x32_bf16(
                    af[i], bf8[j], acc[i][j], 0, 0, 0);
        __syncthreads();
    }

#pragma unroll
    for (int j = 0; j < TN; ++j) {
        const int n = (wn * TN + j) * 16 + ln15;
        const float bj = bias[n];
#pragma unroll
        for (int i = 0; i < TM; ++i) {
#pragma unroll
            for (int r = 0; r < 4; ++r) {
                const int m  = (wm * TM + i) * 16 + kq * 4 + r;
                const int gh = h0 + (m >> 5), gw = w0 + (m & 31);
                const size_t gp = ((size_t)bb * HH + gh) * WW + gw;
                out[gp * COUT + n] = __float2bfloat16(mish_f(acc[i][j][r] + bj));
            }
        }
    }
}

// ---------------------------------------------------------------------------
// BN folded into flow conv: out = SC * sum_{taps in-bounds} (tb[t] + x.fwp[t])
// ---------------------------------------------------------------------------
__global__ __launch_bounds__(256) void bn_flow_kernel(
    const __hip_bfloat16* __restrict__ xin,
    const float* __restrict__ fwp, const float* __restrict__ tbv,
    float* __restrict__ out)
{
    const int pix = blockIdx.x * 256 + threadIdx.x;
    const int wq  = pix % WW;
    const int hq  = (pix / WW) % HH;
    const int bq  = pix / (WW * HH);
    float a0 = 0.f, a1 = 0.f;
#pragma unroll
    for (int dy = -1; dy <= 1; ++dy) {
        const int yy = hq + dy;
        if ((unsigned)yy >= HH) continue;
#pragma unroll
        for (int dx = -1; dx <= 1; ++dx) {
            const int xx = wq + dx;
            if ((unsigned)xx >= WW) continue;
            const int t = (dy + 1) * 3 + (dx + 1);
            a0 += tbv[t * 2 + 0];
            a1 += tbv[t * 2 + 1];
            const short* xp = (const short*)xin + (((size_t)bq * HH + yy) * WW + xx) * 16;
            const short8 v0 = *(const short8*)xp;
            const short8 v1 = *(const short8*)(xp + 8);
            float x[16];
            cvt8(v0, x); cvt8(v1, x + 8);
            const float* wp = fwp + t * 32;
#pragma unroll
            for (int c = 0; c < 16; ++c) {
                a0 += x[c] * wp[c * 2 + 0];
                a1 += x[c] * wp[c * 2 + 1];
            }
        }
    }
    const float SC = sqrtf((float)(HH * HH + WW * WW));
    out[(size_t)pix * 2 + 0] = SC * a0;
    out[(size_t)pix * 2 + 1] = SC * a1;
}

// ---------------------------------------------------------------------------
// Workspace:
// UNIFIED (ws >= ~208 MB): x0b[N][224] | t1[N][128] | wts bf16 | f32 wts
// FALLBACK (ws >= ~133 MB): cv[N][96]  | t1[N][128] | wts bf16 | f32 wts
// t2 = ws[0:N*64], t3 = t1, t4 = ws[N*64:N*80] in both.
// ---------------------------------------------------------------------------
extern "C" void kernel_launch(void* const* d_in, const int* in_sizes, int n_in,
                              void* d_out, int out_size, void* d_ws, size_t ws_size,
                              hipStream_t stream)
{
    const float* prv   = (const float*)d_in[0];
    const float* nxt   = (const float*)d_in[1];
    const float* dw0   = (const float*)d_in[2];
    const float* pw0   = (const float*)d_in[3];
    const float* b0    = (const float*)d_in[4];
    const float* dw1   = (const float*)d_in[5];
    const float* pw1   = (const float*)d_in[6];
    const float* b1    = (const float*)d_in[7];
    const float* dw2   = (const float*)d_in[8];
    const float* pw2   = (const float*)d_in[9];
    const float* b2    = (const float*)d_in[10];
    const float* dw3   = (const float*)d_in[11];
    const float* pw3   = (const float*)d_in[12];
    const float* b3    = (const float*)d_in[13];
    const float* bn_g  = (const float*)d_in[14];
    const float* bn_b  = (const float*)d_in[15];
    const float* bn_m  = (const float*)d_in[16];
    const float* bn_v  = (const float*)d_in[17];
    const float* fw    = (const float*)d_in[18];
    float* outp = (float*)d_out;

    const size_t N = (size_t)NPIX;
    __hip_bfloat16* ws = (__hip_bfloat16*)d_ws;

    const size_t need_uni = (N * 352 + 43456) * 2 + 4338 * 4;
    const bool uni = (ws_size >= need_uni);

    __hip_bfloat16* t1  = uni ? (ws + N * 224) : (ws + N * 96);
    __hip_bfloat16* wts = uni ? (ws + N * 352) : (ws + N * 224);
    __hip_bfloat16* t2  = ws;                    // aliases x0b/cv (dead then)
    __hip_bfloat16* t3  = t1;
    __hip_bfloat16* t4  = ws + N * 64;
    __hip_bfloat16* Bt0 = wts + 4032;
    __hip_bfloat16* Bt1 = wts + 32704;
    __hip_bfloat16* Bt2 = wts + 40896;
    __hip_bfloat16* Bt3 = wts + 42944;
    float* fwt = (float*)(wts + 43456);          // dwf0|dwf1|dwf2|dwf3|fwp|tb

    prep_kernel<<<170, 256, 0, stream>>>(dw0, pw0, dw1, pw1, dw2, pw2, dw3, pw3, wts);
    prep2_kernel<<<17, 256, 0, stream>>>(dw0, dw1, dw2, dw3,
                                         bn_g, bn_b, bn_m, bn_v, fw, fwt);
    if (uni) {
        cost_mfma_kernel<1><<<2304, 256, 0, stream>>>(prv, nxt, ws);
        sepconv_mfma<224, 128, 0><<<2304, 256, 0, stream>>>(ws, nullptr, nullptr,
                                                            fwt, Bt0, b0, t1);
    } else {
        cost_mfma_kernel<0><<<2304, 256, 0, stream>>>(prv, nxt, ws);
        sepconv_mfma<224, 128, 1><<<2304, 256, 0, stream>>>(ws, prv, nxt,
                                                            fwt, Bt0, b0, t1);
    }
    sepconv_mfma<128, 64, 0><<<2304, 256, 0, stream>>>(t1, nullptr, nullptr,
                                                       fwt + 2016, Bt1, b1, t2);
    sepconv_mfma<64, 32, 0><<<2304, 256, 0, stream>>>(t2, nullptr, nullptr,
                                                      fwt + 3168, Bt2, b2, t3);
    sepconv_mfma<32, 16, 0><<<2304, 256, 0, stream>>>(t3, nullptr, nullptr,
                                                      fwt + 3744, Bt3, b3, t4);
    bn_flow_kernel<<<NPIX / 256, 256, 0, stream>>>(t4, fwt + 4032, fwt + 4320, outp);
}

// Round 7
// 488.128 us; speedup vs baseline: 4.3613x; 1.1012x over previous
//
#include <hip/hip_runtime.h>
#include <hip/hip_bf16.h>

// Problem constants
#define BB 8
#define HH 192
#define WW 192
#define CC0 64
#define NPIX (BB*HH*WW) // 294912
#define NCV 81
#define CVP 96          // cv padded channels in fallback layout

typedef __attribute__((ext_vector_type(8))) short short8;
typedef __attribute__((ext_vector_type(4))) short short4v;
typedef __attribute__((ext_vector_type(4))) float f32x4;

__device__ __forceinline__ float bf2f(short s) {
    union { unsigned u; float f; } x; x.u = ((unsigned)(unsigned short)s) << 16; return x.f;
}
__device__ __forceinline__ short f2bf(float f) {
    __hip_bfloat16 h = __float2bfloat16(f);
    return *reinterpret_cast<short*>(&h);
}
__device__ __forceinline__ void cvt8(const short8 iv, float* fv) {
    const int* ip = (const int*)&iv;
#pragma unroll
    for (int e = 0; e < 4; ++e) {
        union { unsigned u; float f; } lo, hi;
        lo.u = ((unsigned)ip[e]) << 16;
        hi.u = ((unsigned)ip[e]) & 0xffff0000u;
        fv[2 * e] = lo.f; fv[2 * e + 1] = hi.f;
    }
}

__device__ __forceinline__ float mish_f(float v) {
    if (v > 20.0f) return v;
    const float u = __expf(v);
    const float n = u * (u + 2.0f);
    return v * n / (n + 2.0f);
}

// ---------------------------------------------------------------------------
// Weight prep (bf16 Bt matrices, channel order [prv|nxt|cv|pad]) — as R4.
// ---------------------------------------------------------------------------
__global__ __launch_bounds__(256) void prep_kernel(
    const float* __restrict__ dw0, const float* __restrict__ pw0,
    const float* __restrict__ dw1, const float* __restrict__ pw1,
    const float* __restrict__ dw2, const float* __restrict__ pw2,
    const float* __restrict__ dw3, const float* __restrict__ pw3,
    __hip_bfloat16* __restrict__ wout)
{
    const int u = blockIdx.x * 256 + threadIdx.x;
    if (u >= 43456) return;
    float v = 0.f;
    if (u < 2016) {                     // legacy dwbf0 slot (unused, kept for layout)
        const int t = u / 224, c = u % 224;
        if (c < 64)       v = dw0[t*209 + 81  + c];
        else if (c < 128) v = dw0[t*209 + 145 + (c-64)];
        else if (c < 209) v = dw0[t*209 + (c-128)];
    } else if (u < 3168) {
        const int r = u-2016, t = r/128, c = r%128; v = dw1[t*128+c];
    } else if (u < 3744) {
        const int r = u-3168, t = r/64, c = r%64; v = dw2[t*64+c];
    } else if (u < 4032) {
        const int r = u-3744, t = r/32, c = r%32; v = dw3[t*32+c];
    } else if (u < 32704) {             // Bt0 [128][224]
        const int r = u-4032, n = r/224, c = r%224;
        if (c < 64)       v = pw0[(81+c)*128 + n];
        else if (c < 128) v = pw0[(145+(c-64))*128 + n];
        else if (c < 209) v = pw0[(c-128)*128 + n];
    } else if (u < 40896) {             // Bt1 [64][128]
        const int r = u-32704, n = r/128, c = r%128; v = pw1[c*64 + n];
    } else if (u < 42944) {             // Bt2 [32][64]
        const int r = u-40896, n = r/64, c = r%64; v = pw2[c*32 + n];
    } else {                            // Bt3 [16][32]
        const int r = u-42944, n = r/32, c = r%32; v = pw3[c*16 + n];
    }
    wout[u] = __float2bfloat16(v);
}

// ---------------------------------------------------------------------------
// prep2: f32 dw weights (stage0 permuted to [prv|nxt|cv|pad]) + fused BN*flow
// weights. fout: dwf0[2016] dwf1[1152] dwf2[576] dwf3[288] fwp[288] tb[18]
// ---------------------------------------------------------------------------
__global__ __launch_bounds__(256) void prep2_kernel(
    const float* __restrict__ dw0, const float* __restrict__ dw1,
    const float* __restrict__ dw2, const float* __restrict__ dw3,
    const float* __restrict__ bn_g, const float* __restrict__ bn_b,
    const float* __restrict__ bn_m, const float* __restrict__ bn_v,
    const float* __restrict__ fw, float* __restrict__ fout)
{
    const int u = blockIdx.x * 256 + threadIdx.x;
    if (u >= 4338) return;
    float v = 0.f;
    if (u < 2016) {
        const int t = u / 224, c = u % 224;
        if (c < 64)       v = dw0[t*209 + 81  + c];
        else if (c < 128) v = dw0[t*209 + 145 + (c-64)];
        else if (c < 209) v = dw0[t*209 + (c-128)];
    } else if (u < 3168) {
        const int r = u-2016, t = r/128, c = r%128; v = dw1[t*128+c];
    } else if (u < 3744) {
        const int r = u-3168, t = r/64, c = r%64; v = dw2[t*64+c];
    } else if (u < 4032) {
        const int r = u-3744, t = r/32, c = r%32; v = dw3[t*32+c];
    } else if (u < 4320) {              // fwp[t][c][s] = sc[c]*fw[t][c][s]
        const int r = u-4032, t = r/32, rem = r%32, c = rem >> 1, s = rem & 1;
        const float sc = bn_g[c] * rsqrtf(bn_v[c] + 1e-3f);
        v = sc * fw[t*32 + c*2 + s];
    } else {                            // tb[t][s] = sum_c sh[c]*fw[t][c][s]
        const int r = u-4320, t = r/2, s = r%2;
        float a = 0.f;
        for (int c = 0; c < 16; ++c) {
            const float sc = bn_g[c] * rsqrtf(bn_v[c] + 1e-3f);
            const float sh = bn_b[c] - bn_m[c] * sc;
            a += sh * fw[t*32 + c*2 + s];
        }
        v = a;
    }
    fout[u] = v;
}

// ---------------------------------------------------------------------------
// Cost volume v2 (R6 structure, passed): MFMA banded QK^T, 32x4 tile,
// double-buffered sNxt with register prefetch.
// ---------------------------------------------------------------------------
template<int UNIFIED>
__global__ __launch_bounds__(256) void cost_mfma_kernel(
    const float* __restrict__ prv, const float* __restrict__ nxt,
    __hip_bfloat16* __restrict__ xout)
{
    constexpr int OST   = UNIFIED ? 224 : CVP;
    constexpr int CVOFF = UNIFIED ? 128 : 0;

    __shared__ __align__(16) short sNxt[2][48][70];
    __shared__ __align__(16) short sCv[4][32][96];

    const int tid  = threadIdx.x;
    const int lane = tid & 63;
    const int wv   = tid >> 6;
    const int ln15 = lane & 15;
    const int kq   = lane >> 4;
    const int mt   = wv & 1;
    const int jt   = wv >> 1;

    const int bx = blockIdx.x;
    const int tw = bx % 6;
    const int th = (bx / 6) % 48;
    const int b  = bx / 288;
    const int w0 = tw * 32, h0 = th * 4;

    {
        const short8 z = {0,0,0,0,0,0,0,0};
#pragma unroll
        for (int t = 0; t < 6; ++t) {
            const int idx = tid + t * 256;
            const int row = idx / 384, rem = idx % 384;
            const int px = rem / 12, c8 = rem % 12;
            *(short8*)&sCv[row][px][c8 * 8] = z;
        }
    }

    short8 af0[4], af1[4];
    {
        const int apx = w0 + mt * 16 + ln15;
#pragma unroll
        for (int r4 = 0; r4 < 4; ++r4) {
            const float* ap = prv + (((size_t)b * HH + h0 + r4) * WW + apx) * CC0 + kq * 8;
            const float4 x0 = *(const float4*)(ap);
            const float4 x1 = *(const float4*)(ap + 4);
            const float4 x2 = *(const float4*)(ap + 32);
            const float4 x3 = *(const float4*)(ap + 36);
            af0[r4][0]=f2bf(x0.x); af0[r4][1]=f2bf(x0.y); af0[r4][2]=f2bf(x0.z); af0[r4][3]=f2bf(x0.w);
            af0[r4][4]=f2bf(x1.x); af0[r4][5]=f2bf(x1.y); af0[r4][6]=f2bf(x1.z); af0[r4][7]=f2bf(x1.w);
            af1[r4][0]=f2bf(x2.x); af1[r4][1]=f2bf(x2.y); af1[r4][2]=f2bf(x2.z); af1[r4][3]=f2bf(x2.w);
            af1[r4][4]=f2bf(x3.x); af1[r4][5]=f2bf(x3.y); af1[r4][6]=f2bf(x3.z); af1[r4][7]=f2bf(x3.w);
        }
    }

    int cur = 0;
    {
        const int y0 = h0 - 4;
        if ((unsigned)y0 < (unsigned)HH) {
            const float* rowp = nxt + (((size_t)b * HH + y0) * WW) * CC0;
#pragma unroll
            for (int t = 0; t < 3; ++t) {
                const int u = tid + t * 256;
                if (u < 640) {
                    const int px = u >> 4, c4 = u & 15;
                    const int gw = w0 - 4 + px;
                    float4 v = make_float4(0.f, 0.f, 0.f, 0.f);
                    if ((unsigned)gw < (unsigned)WW)
                        v = *(const float4*)(rowp + (size_t)gw * CC0 + c4 * 4);
                    short4v sv;
                    sv[0]=f2bf(v.x); sv[1]=f2bf(v.y); sv[2]=f2bf(v.z); sv[3]=f2bf(v.w);
                    *(short4v*)&sNxt[0][px][c4 * 4] = sv;
                }
            }
        }
    }

    const size_t obase_blk = (((size_t)b * HH + h0) * WW + w0);

    for (int i = 0; i < 12; ++i) {
        const int y = h0 - 4 + i;
        const bool yok = ((unsigned)y < (unsigned)HH);
        __syncthreads();

        const int yn = y + 1;
        const bool nok = (i < 11) && ((unsigned)yn < (unsigned)HH);
        float4 sreg[3];
        if (nok) {
            const float* rowp = nxt + (((size_t)b * HH + yn) * WW) * CC0;
#pragma unroll
            for (int t = 0; t < 3; ++t) {
                const int u = tid + t * 256;
                sreg[t] = make_float4(0.f, 0.f, 0.f, 0.f);
                if (u < 640) {
                    const int px = u >> 4, c4 = u & 15;
                    const int gw = w0 - 4 + px;
                    if ((unsigned)gw < (unsigned)WW)
                        sreg[t] = *(const float4*)(rowp + (size_t)gw * CC0 + c4 * 4);
                }
            }
        }

        if (yok) {
            const int nb = mt * 16 + jt * 16 + ln15;
            const short* bp = &sNxt[cur][nb][kq * 8];
            const short8 b0 = *(const short8*)bp;
            const short8 b1 = *(const short8*)(bp + 32);
#pragma unroll
            for (int r4 = 0; r4 < 4; ++r4) {
                const int h = h0 + r4;
                const int rband = y - h + 4;
                if ((unsigned)rband <= 8u) {
                    f32x4 acc = {0.f, 0.f, 0.f, 0.f};
                    acc = __builtin_amdgcn_mfma_f32_16x16x32_bf16(af0[r4], b0, acc, 0, 0, 0);
                    acc = __builtin_amdgcn_mfma_f32_16x16x32_bf16(af1[r4], b1, acc, 0, 0, 0);
#pragma unroll
                    for (int rr = 0; rr < 4; ++rr) {
                        const int m_local = kq * 4 + rr;
                        const int dj = jt * 16 + ln15 - m_local;
                        if ((unsigned)dj < 9u) {
                            float mv = acc[rr] * (1.0f / 64.0f);
                            mv = (mv > 0.f) ? mv : 0.1f * mv;
                            sCv[r4][mt * 16 + m_local][rband * 9 + dj] = f2bf(mv);
                        }
                    }
                }
            }
            if (UNIFIED && y >= h0 && y < h0 + 4) {
                const int px_o = tid >> 3, cg = tid & 7;
                short* op = (short*)xout + (((size_t)b * HH + y) * WW + w0 + px_o) * OST
                            + 64 + cg * 8;
                *(short8*)op = *(const short8*)&sNxt[cur][4 + px_o][cg * 8];
            }
        }

        if (nok) {
#pragma unroll
            for (int t = 0; t < 3; ++t) {
                const int u = tid + t * 256;
                if (u < 640) {
                    const int px = u >> 4, c4 = u & 15;
                    short4v sv;
                    sv[0]=f2bf(sreg[t].x); sv[1]=f2bf(sreg[t].y);
                    sv[2]=f2bf(sreg[t].z); sv[3]=f2bf(sreg[t].w);
                    *(short4v*)&sNxt[cur ^ 1][px][c4 * 4] = sv;
                }
            }
        }
        cur ^= 1;
    }

    __syncthreads();
#pragma unroll
    for (int t = 0; t < 6; ++t) {
        const int idx = tid + t * 256;
        const int row = idx / 384, rem = idx % 384;
        const int px = rem / 12, c8 = rem % 12;
        short* op = (short*)xout + (obase_blk + (size_t)row * WW + px) * OST + CVOFF + c8 * 8;
        *(short8*)op = *(const short8*)&sCv[row][px][c8 * 8];
    }
    if (UNIFIED) {
#pragma unroll
        for (int t = 0; t < 4; ++t) {
            const int u = tid + t * 256;
            const int row = u >> 8, px = (u >> 3) & 31, cg = u & 7;
            const float* ap = prv + (obase_blk + (size_t)row * WW + px) * CC0 + cg * 8;
            const float4 x0 = *(const float4*)(ap);
            const float4 x1 = *(const float4*)(ap + 4);
            short8 v;
            v[0]=f2bf(x0.x); v[1]=f2bf(x0.y); v[2]=f2bf(x0.z); v[3]=f2bf(x0.w);
            v[4]=f2bf(x1.x); v[5]=f2bf(x1.y); v[6]=f2bf(x1.z); v[7]=f2bf(x1.w);
            short* op = (short*)xout + (obase_blk + (size_t)row * WW + px) * OST + cg * 8;
            *(short8*)op = v;
        }
    }
}

// ---------------------------------------------------------------------------
// Fused sepconv v2: SOFTWARE-PIPELINED.
// Per chunk: write prefetched regs -> sIn, barrier, ISSUE next chunk's global
// loads (regs) + this chunk's B-frag loads (L2-hot Bt, no LDS staging),
// dw compute -> sA, barrier, MFMA. Global latency hidden behind dw+MFMA.
// Single-buffered LDS is race-free: sIn writes happen only after barrier2 of
// the previous chunk; sA overwrites only after barrier1 (implied waitcnt has
// drained the previous MFMA's frag ds_reads).
// ---------------------------------------------------------------------------
template<int KP, int COUT, int MODE>
__global__ __launch_bounds__(256) void sepconv_mfma(
    const __hip_bfloat16* __restrict__ in,
    const float* __restrict__ prv, const float* __restrict__ nxt,
    const float* __restrict__ dwf,             // [9][KP] f32
    const __hip_bfloat16* __restrict__ Bt,     // [COUT][KP]
    const float* __restrict__ bias,
    __hip_bfloat16* __restrict__ out)
{
    constexpr int NC  = KP / 32;
    constexpr int NT  = COUT / 16;
    constexpr int WGN = (NT >= 2) ? 2 : 1;
    constexpr int WGM = 4 / WGN;
    constexpr int TM  = 8 / WGM;
    constexpr int TN  = NT / WGN;

    __shared__ __align__(16) short sIn[6][34][32];   // 13056 B
    __shared__ __align__(16) short sA[4][128][8];    //  8192 B

    const int tid  = threadIdx.x;
    const int lane = tid & 63;
    const int wv   = tid >> 6;
    const int ln15 = lane & 15;
    const int kq   = lane >> 4;
    const int wm   = wv % WGM;
    const int wn   = wv / WGM;

    const int bx = blockIdx.x;
    const int tw = bx % 6;
    const int th = (bx / 6) % 48;
    const int bb = bx / 288;
    const int w0 = tw * 32, h0 = th * 4;

    // depthwise mapping: wave-uniform k-slice (SGPR weights), lane = px
    const int dkbu = __builtin_amdgcn_readfirstlane(wv);
    const int dww  = lane & 31;
    const int dhh  = (lane >> 5) * 2;

    // staging-unit loader: unit u in [0,816) = (px p=u>>2, kblock kb=u&3)
    auto load_unit = [&](int u, int k0) -> short8 {
        const int kb = u & 3;
        const int p  = u >> 2;
        const int iw = p % 34, ih = p / 34;
        const int gw = w0 - 1 + iw, gh = h0 - 1 + ih;
        short8 v = {0,0,0,0,0,0,0,0};
        if ((unsigned)gw < (unsigned)WW && (unsigned)gh < (unsigned)HH) {
            const size_t pix = ((size_t)bb * HH + gh) * WW + gw;
            const int c0 = k0 + kb * 8;
            if (MODE == 0) {
                v = *(const short8*)((const short*)in + pix * KP + c0);
            } else {
                if (c0 < 64) {
                    const float4* s = (const float4*)(prv + pix * 64 + c0);
                    const float4 a = s[0], bq = s[1];
                    v[0]=f2bf(a.x);  v[1]=f2bf(a.y);  v[2]=f2bf(a.z);  v[3]=f2bf(a.w);
                    v[4]=f2bf(bq.x); v[5]=f2bf(bq.y); v[6]=f2bf(bq.z); v[7]=f2bf(bq.w);
                } else if (c0 < 128) {
                    const float4* s = (const float4*)(nxt + pix * 64 + (c0 - 64));
                    const float4 a = s[0], bq = s[1];
                    v[0]=f2bf(a.x);  v[1]=f2bf(a.y);  v[2]=f2bf(a.z);  v[3]=f2bf(a.w);
                    v[4]=f2bf(bq.x); v[5]=f2bf(bq.y); v[6]=f2bf(bq.z); v[7]=f2bf(bq.w);
                } else {
                    v = *(const short8*)((const short*)in + pix * CVP + (c0 - 128));
                }
            }
        }
        return v;
    };

    f32x4 acc[TM][TN] = {};
    short8 pr[4];

    // prologue: prefetch chunk 0
#pragma unroll
    for (int t = 0; t < 4; ++t) {
        const int u = tid + t * 256;
        pr[t] = (u < 816) ? load_unit(u, 0) : short8{0,0,0,0,0,0,0,0};
    }

#pragma unroll
    for (int c = 0; c < NC; ++c) {
        const int k0 = c * 32;
        // --- commit prefetched staging to LDS (flat offset = u*16B) ---
#pragma unroll
        for (int t = 0; t < 4; ++t) {
            const int u = tid + t * 256;
            if (u < 816) *(short8*)((short*)sIn + (size_t)u * 8) = pr[t];
        }
        __syncthreads();

        // --- issue next chunk's global loads (hidden behind dw+MFMA) ---
        if (c + 1 < NC) {
#pragma unroll
            for (int t = 0; t < 4; ++t) {
                const int u = tid + t * 256;
                if (u < 816) pr[t] = load_unit(u, k0 + 32);
            }
        }
        // --- B-frags direct from global (Bt is L2-resident) ---
        short8 bfr[TN];
#pragma unroll
        for (int j = 0; j < TN; ++j) {
            const int n = (wn * TN + j) * 16 + ln15;
            bfr[j] = *(const short8*)((const short*)Bt + (size_t)n * KP + k0 + kq * 8);
        }

        // --- depthwise: 2 vertically-adjacent px, 8 ch; f32 SGPR weights ---
        {
            const float* wrow = dwf + k0 + dkbu * 8;
            float r0[8] = {0,0,0,0,0,0,0,0};
            float r1[8] = {0,0,0,0,0,0,0,0};
#pragma unroll
            for (int dy = 0; dy < 4; ++dy) {
#pragma unroll
                for (int dx = 0; dx < 3; ++dx) {
                    const short8 iv = *(const short8*)&sIn[dhh + dy][dww + dx][dkbu * 8];
                    float fv[8];
                    cvt8(iv, fv);
                    if (dy < 3) {
#pragma unroll
                        for (int j = 0; j < 8; ++j)
                            r0[j] += fv[j] * wrow[(dy * 3 + dx) * KP + j];
                    }
                    if (dy >= 1) {
#pragma unroll
                        for (int j = 0; j < 8; ++j)
                            r1[j] += fv[j] * wrow[((dy - 1) * 3 + dx) * KP + j];
                    }
                }
            }
            const int px0 = dhh * 32 + dww;
            short8 o0, o1;
#pragma unroll
            for (int j = 0; j < 8; ++j) { o0[j] = f2bf(r0[j]); o1[j] = f2bf(r1[j]); }
            *(short8*)&sA[dkbu][px0 ^ (dkbu << 2)][0] = o0;
            *(short8*)&sA[dkbu][(px0 + 32) ^ (dkbu << 2)][0] = o1;
        }
        __syncthreads();

        // --- MFMA ---
        short8 af[TM];
#pragma unroll
        for (int i = 0; i < TM; ++i) {
            const int m = (wm * TM + i) * 16 + ln15;
            af[i] = *(const short8*)&sA[kq][m ^ (kq << 2)][0];
        }
#pragma unroll
        for (int i = 0; i < TM; ++i)
#pragma unroll
            for (int j = 0; j < TN; ++j)
                acc[i][j] = __builtin_amdgcn_mfma_f32_16x16x32_bf16(
                    af[i], bfr[j], acc[i][j], 0, 0, 0);
    }

#pragma unroll
    for (int j = 0; j < TN; ++j) {
        const int n = (wn * TN + j) * 16 + ln15;
        const float bj = bias[n];
#pragma unroll
        for (int i = 0; i < TM; ++i) {
#pragma unroll
            for (int r = 0; r < 4; ++r) {
                const int m  = (wm * TM + i) * 16 + kq * 4 + r;
                const int gh = h0 + (m >> 5), gw = w0 + (m & 31);
                const size_t gp = ((size_t)bb * HH + gh) * WW + gw;
                out[gp * COUT + n] = __float2bfloat16(mish_f(acc[i][j][r] + bj));
            }
        }
    }
}

// ---------------------------------------------------------------------------
// BN folded into flow conv: out = SC * sum_{taps in-bounds} (tb[t] + x.fwp[t])
// ---------------------------------------------------------------------------
__global__ __launch_bounds__(256) void bn_flow_kernel(
    const __hip_bfloat16* __restrict__ xin,
    const float* __restrict__ fwp, const float* __restrict__ tbv,
    float* __restrict__ out)
{
    const int pix = blockIdx.x * 256 + threadIdx.x;
    const int wq  = pix % WW;
    const int hq  = (pix / WW) % HH;
    const int bq  = pix / (WW * HH);
    float a0 = 0.f, a1 = 0.f;
#pragma unroll
    for (int dy = -1; dy <= 1; ++dy) {
        const int yy = hq + dy;
        if ((unsigned)yy >= HH) continue;
#pragma unroll
        for (int dx = -1; dx <= 1; ++dx) {
            const int xx = wq + dx;
            if ((unsigned)xx >= WW) continue;
            const int t = (dy + 1) * 3 + (dx + 1);
            a0 += tbv[t * 2 + 0];
            a1 += tbv[t * 2 + 1];
            const short* xp = (const short*)xin + (((size_t)bq * HH + yy) * WW + xx) * 16;
            const short8 v0 = *(const short8*)xp;
            const short8 v1 = *(const short8*)(xp + 8);
            float x[16];
            cvt8(v0, x); cvt8(v1, x + 8);
            const float* wp = fwp + t * 32;
#pragma unroll
            for (int c = 0; c < 16; ++c) {
                a0 += x[c] * wp[c * 2 + 0];
                a1 += x[c] * wp[c * 2 + 1];
            }
        }
    }
    const float SC = sqrtf((float)(HH * HH + WW * WW));
    out[(size_t)pix * 2 + 0] = SC * a0;
    out[(size_t)pix * 2 + 1] = SC * a1;
}

// ---------------------------------------------------------------------------
// Workspace:
// UNIFIED (ws >= ~208 MB): x0b[N][224] | t1[N][128] | wts bf16 | f32 wts
// FALLBACK (ws >= ~133 MB): cv[N][96]  | t1[N][128] | wts bf16 | f32 wts
// t2 = ws[0:N*64], t3 = t1, t4 = ws[N*64:N*80] in both.
// ---------------------------------------------------------------------------
extern "C" void kernel_launch(void* const* d_in, const int* in_sizes, int n_in,
                              void* d_out, int out_size, void* d_ws, size_t ws_size,
                              hipStream_t stream)
{
    const float* prv   = (const float*)d_in[0];
    const float* nxt   = (const float*)d_in[1];
    const float* dw0   = (const float*)d_in[2];
    const float* pw0   = (const float*)d_in[3];
    const float* b0    = (const float*)d_in[4];
    const float* dw1   = (const float*)d_in[5];
    const float* pw1   = (const float*)d_in[6];
    const float* b1    = (const float*)d_in[7];
    const float* dw2   = (const float*)d_in[8];
    const float* pw2   = (const float*)d_in[9];
    const float* b2    = (const float*)d_in[10];
    const float* dw3   = (const float*)d_in[11];
    const float* pw3   = (const float*)d_in[12];
    const float* b3    = (const float*)d_in[13];
    const float* bn_g  = (const float*)d_in[14];
    const float* bn_b  = (const float*)d_in[15];
    const float* bn_m  = (const float*)d_in[16];
    const float* bn_v  = (const float*)d_in[17];
    const float* fw    = (const float*)d_in[18];
    float* outp = (float*)d_out;

    const size_t N = (size_t)NPIX;
    __hip_bfloat16* ws = (__hip_bfloat16*)d_ws;

    const size_t need_uni = (N * 352 + 43456) * 2 + 4338 * 4;
    const bool uni = (ws_size >= need_uni);

    __hip_bfloat16* t1  = uni ? (ws + N * 224) : (ws + N * 96);
    __hip_bfloat16* wts = uni ? (ws + N * 352) : (ws + N * 224);
    __hip_bfloat16* t2  = ws;                    // aliases x0b/cv (dead then)
    __hip_bfloat16* t3  = t1;
    __hip_bfloat16* t4  = ws + N * 64;
    __hip_bfloat16* Bt0 = wts + 4032;
    __hip_bfloat16* Bt1 = wts + 32704;
    __hip_bfloat16* Bt2 = wts + 40896;
    __hip_bfloat16* Bt3 = wts + 42944;
    float* fwt = (float*)(wts + 43456);          // dwf0|dwf1|dwf2|dwf3|fwp|tb

    prep_kernel<<<170, 256, 0, stream>>>(dw0, pw0, dw1, pw1, dw2, pw2, dw3, pw3, wts);
    prep2_kernel<<<17, 256, 0, stream>>>(dw0, dw1, dw2, dw3,
                                         bn_g, bn_b, bn_m, bn_v, fw, fwt);
    if (uni) {
        cost_mfma_kernel<1><<<2304, 256, 0, stream>>>(prv, nxt, ws);
        sepconv_mfma<224, 128, 0><<<2304, 256, 0, stream>>>(ws, nullptr, nullptr,
                                                            fwt, Bt0, b0, t1);
    } else {
        cost_mfma_kernel<0><<<2304, 256, 0, stream>>>(prv, nxt, ws);
        sepconv_mfma<224, 128, 1><<<2304, 256, 0, stream>>>(ws, prv, nxt,
                                                            fwt, Bt0, b0, t1);
    }
    sepconv_mfma<128, 64, 0><<<2304, 256, 0, stream>>>(t1, nullptr, nullptr,
                                                       fwt + 2016, Bt1, b1, t2);
    sepconv_mfma<64, 32, 0><<<2304, 256, 0, stream>>>(t2, nullptr, nullptr,
                                                      fwt + 3168, Bt2, b2, t3);
    sepconv_mfma<32, 16, 0><<<2304, 256, 0, stream>>>(t3, nullptr, nullptr,
                                                      fwt + 3744, Bt3, b3, t4);
    bn_flow_kernel<<<NPIX / 256, 256, 0, stream>>>(t4, fwt + 4032, fwt + 4320, outp);
}